// Round 9
// baseline (260.156 us; speedup 1.0000x reference)
//
#include <hip/hip_runtime.h>
#include <hip/hip_bf16.h>

#define Bq 4
#define Nq 2048
#define Cq 256
#define Dq 64
#define UPq 4
#define KNNq 20
#define PHq 64
#define DMq 256   // D*MULT
#define PTS 16    // points per block in k_value

typedef __attribute__((ext_vector_type(8))) short short8;
typedef __attribute__((ext_vector_type(4))) short short4v;
typedef __attribute__((ext_vector_type(4))) float f32x4;
typedef __hip_bfloat16 bf16;

__device__ __forceinline__ unsigned short f2b(float x){
  bf16 h = __float2bfloat16(x);
  return *reinterpret_cast<unsigned short*>(&h);
}
__device__ __forceinline__ float b2f(short s){
  return __bfloat162float(*reinterpret_cast<bf16*>(&s));
}

// ---------------------------------------------------------------------------
// Kernel 0: weight prep — emit bf16 weights in MFMA A-fragment-swizzled order:
// dst[((mt*KS+ks)*64+lane)*8+j] = W[mt*16+(lane&15)][ks*32+(lane>>4)*8+j]
// aw1 additionally gets the attn-BN scale folded in (row scale ag*rsqrt(arv+eps)).
// ---------------------------------------------------------------------------
__device__ __forceinline__ void swz(const float* __restrict__ src,
                                    short* __restrict__ dst,
                                    int M, int K, int g, bool transp)
{
  int j = g & 7, lane = (g >> 3) & 63, rest = g >> 9;
  int KS = K >> 5;
  int ks = rest % KS, mt = rest / KS;
  int m = mt*16 + (lane & 15);
  int k = ks*32 + ((lane >> 4) << 3) + j;
  float v = transp ? src[k*M + m] : src[m*K + k];
  dst[g] = (short)f2b(v);
}

__device__ __forceinline__ void swz_s(const float* __restrict__ src,
                                      short* __restrict__ dst,
                                      int M, int K, int g,
                                      const float* __restrict__ gam,
                                      const float* __restrict__ var)
{
  int j = g & 7, lane = (g >> 3) & 63, rest = g >> 9;
  int KS = K >> 5;
  int ks = rest % KS, mt = rest / KS;
  int m = mt*16 + (lane & 15);
  int k = ks*32 + ((lane >> 4) << 3) + j;
  float sc = gam[m] * rsqrtf(var[m] + 1e-5f);
  dst[g] = (short)f2b(src[m*K + k] * sc);
}

__global__ __launch_bounds__(256) void k_prep(
    const float* __restrict__ aw1, const float* __restrict__ ctw,
    const float* __restrict__ wv1, const float* __restrict__ wvs,
    const float* __restrict__ wv2, const float* __restrict__ wk,
    const float* __restrict__ wq,  const float* __restrict__ wval,
    const float* __restrict__ pw2, const float* __restrict__ we,
    short* __restrict__ aw1b, short* __restrict__ ctwT,
    short* __restrict__ wv1b, short* __restrict__ wvsb,
    short* __restrict__ wv2b, short* __restrict__ wkb,
    short* __restrict__ wqb,  short* __restrict__ wvalb,
    short* __restrict__ pw2b, short* __restrict__ web,
    const float* __restrict__ ag, const float* __restrict__ arv)
{
  const int t = threadIdx.x, bidx = blockIdx.x;
  if (bidx < 512){
    swz(wv1, wv1b, 256, 512, bidx*256 + t, false);
  } else if (bidx < 1024){
    swz(wvs, wvsb, 256, 512, (bidx-512)*256 + t, false);
  } else if (bidx < 1280){
    swz(wv2, wv2b, 256, 256, (bidx-1024)*256 + t, false);
  } else if (bidx < 1344){
    swz(wk, wkb, 64, 256, (bidx-1280)*256 + t, false);
  } else if (bidx < 1408){
    swz(wq, wqb, 64, 256, (bidx-1344)*256 + t, false);
  } else if (bidx < 1472){
    swz(wval, wvalb, 64, 256, (bidx-1408)*256 + t, false);
  } else if (bidx < 1488){
    swz(pw2, pw2b, 64, 64, (bidx-1472)*256 + t, false);
  } else if (bidx < 1552){
    swz_s(aw1, aw1b, 256, 64, (bidx-1488)*256 + t, ag, arv);  // BN scale folded in
  } else if (bidx < 1616){
    swz(we, web, 256, 64, (bidx-1552)*256 + t, false);
  } else {
    swz(ctw, ctwT, 256, 256, (bidx-1616)*256 + t, true);  // W[m=t_out][k=c] = ctw[c][t_out]
  }
}

// ---------------------------------------------------------------------------
// Kernel 1: FUSED value-MLP + KNN ("k_vk").  (round-6 verified)
// ---------------------------------------------------------------------------
__global__ __launch_bounds__(256, 4) void k_vk(
    const float* __restrict__ key, const float* __restrict__ query,
    const short* __restrict__ wv1b, const short* __restrict__ wvsb,
    const short* __restrict__ wv2b, const short* __restrict__ wkb,
    const short* __restrict__ wqb,  const short* __restrict__ wvalb,
    const float* __restrict__ bv1, const float* __restrict__ bv2,
    const float* __restrict__ bvs, const float* __restrict__ bk,
    const float* __restrict__ bq,  const float* __restrict__ bval,
    float* __restrict__ valueT, short* __restrict__ kfT,
    short* __restrict__ qfT,    short* __restrict__ vfT,
    const float* __restrict__ pos, int* __restrict__ idxT)
{
  const int t = threadIdx.x;
  const int lane = t & 63, w = t >> 6;
  const int vb = blockIdx.x / 5, rem = blockIdx.x % 5;

  if (rem == 4){
    // ================= value path (block vb of 512) =================
    __shared__ __align__(16) short Xb[16*520];
    __shared__ __align__(16) short hidB[16*264];
    __shared__ __align__(16) short valB[16*264];
    const int b = vb >> 7;
    const int n0 = (vb & 127) * PTS;
    const int quad = lane >> 4, l15 = lane & 15;

    {
      const int c4 = t >> 2, pq = t & 3;
      #pragma unroll
      for (int pass=0; pass<4; pass++){
        int c = pass*64 + c4;
        float4 kv = *reinterpret_cast<const float4*>(key   + ((size_t)(b*Cq+c))*Nq + n0 + pq*4);
        float4 qv = *reinterpret_cast<const float4*>(query + ((size_t)(b*Cq+c))*Nq + n0 + pq*4);
        const float* kf_ = (const float*)&kv;
        const float* qf_ = (const float*)&qv;
        #pragma unroll
        for (int i=0;i<4;i++){
          Xb[(pq*4+i)*520 + c]       = (short)f2b(kf_[i]);
          Xb[(pq*4+i)*520 + 256 + c] = (short)f2b(qf_[i]);
        }
      }
    }
    __syncthreads();

    f32x4 acc1[4], accS[4];
    #pragma unroll
    for (int jm=0;jm<4;jm++){ acc1[jm]=(f32x4)0.f; accS[jm]=(f32x4)0.f; }

    #pragma unroll
    for (int ks=0;ks<16;ks++){
      const int kcol = ks*32 + quad*8;
      short8 xb = *reinterpret_cast<const short8*>(&Xb[l15*520 + kcol]);
      #pragma unroll
      for (int jm=0;jm<4;jm++){
        int mt = w*4 + jm;
        short8 a1 = *reinterpret_cast<const short8*>(wv1b + ((mt*16+ks)*64 + lane)*8);
        short8 as = *reinterpret_cast<const short8*>(wvsb + ((mt*16+ks)*64 + lane)*8);
        acc1[jm] = __builtin_amdgcn_mfma_f32_16x16x32_bf16(a1, xb, acc1[jm], 0,0,0);
        accS[jm] = __builtin_amdgcn_mfma_f32_16x16x32_bf16(as, xb, accS[jm], 0,0,0);
      }
    }
    #pragma unroll
    for (int jm=0;jm<4;jm++){
      #pragma unroll
      for (int r=0;r<4;r++){
        int h = (w*4+jm)*16 + quad*4 + r;
        hidB[l15*264 + h] = (short)f2b(fmaxf(acc1[jm][r] + bv1[h], 0.f));
      }
    }
    __syncthreads();

    #pragma unroll
    for (int ks=0;ks<8;ks++){
      const int kcol = ks*32 + quad*8;
      short8 hb = *reinterpret_cast<const short8*>(&hidB[l15*264 + kcol]);
      #pragma unroll
      for (int jm=0;jm<4;jm++){
        int mt = w*4 + jm;
        short8 a = *reinterpret_cast<const short8*>(wv2b + ((mt*8+ks)*64 + lane)*8);
        accS[jm] = __builtin_amdgcn_mfma_f32_16x16x32_bf16(a, hb, accS[jm], 0,0,0);
      }
    }
    #pragma unroll
    for (int jm=0;jm<4;jm++){
      const int cb = (w*4+jm)*16 + quad*4;
      float4 v4;
      #pragma unroll
      for (int r=0;r<4;r++){
        int c = cb + r;
        float v = accS[jm][r] + bv2[c] + bvs[c];
        ((float*)&v4)[r] = v;
        valB[l15*264 + c] = (short)f2b(v);
      }
      // direct fp32 write of value (identity path), 16B contiguous
      *reinterpret_cast<float4*>(valueT + ((size_t)(b*Nq + n0 + l15))*Cq + cb) = v4;
    }
    __syncthreads();

    {
      f32x4 pk4=(f32x4)0.f, pq4=(f32x4)0.f, pv4=(f32x4)0.f;
      #pragma unroll
      for (int ks=0;ks<8;ks++){
        const int kcol = ks*32 + quad*8;
        short8 xk = *reinterpret_cast<const short8*>(&Xb[l15*520 + kcol]);
        short8 xq = *reinterpret_cast<const short8*>(&Xb[l15*520 + 256 + kcol]);
        short8 xv = *reinterpret_cast<const short8*>(&valB[l15*264 + kcol]);
        short8 ak = *reinterpret_cast<const short8*>(wkb  + ((w*8+ks)*64 + lane)*8);
        short8 aq = *reinterpret_cast<const short8*>(wqb  + ((w*8+ks)*64 + lane)*8);
        short8 av = *reinterpret_cast<const short8*>(wvalb+ ((w*8+ks)*64 + lane)*8);
        pk4 = __builtin_amdgcn_mfma_f32_16x16x32_bf16(ak, xk, pk4, 0,0,0);
        pq4 = __builtin_amdgcn_mfma_f32_16x16x32_bf16(aq, xq, pq4, 0,0,0);
        pv4 = __builtin_amdgcn_mfma_f32_16x16x32_bf16(av, xv, pv4, 0,0,0);
      }
      short4v ok, oq, ov;
      #pragma unroll
      for (int r=0;r<4;r++){
        int o = w*16 + quad*4 + r;
        ok[r] = (short)f2b(pk4[r] + bk[o]);
        oq[r] = (short)f2b(pq4[r] + bq[o]);
        ov[r] = (short)f2b(pv4[r] + bval[o]);
      }
      int n = n0 + l15;
      size_t base = ((size_t)(b*Nq+n))*Dq + w*16 + quad*4;
      *reinterpret_cast<short4v*>(kfT + base) = ok;
      *reinterpret_cast<short4v*>(qfT + base) = oq;
      *reinterpret_cast<short4v*>(vfT + base) = ov;
    }
  } else {
    // ================= knn path (block kb of 2048) =================
    const int kb = vb*4 + rem;
    const int pid = kb*4 + w;
    const int b = pid >> 11;
    const int n = pid & (Nq-1);
    const float* px = pos + (size_t)(b*3+0)*Nq;
    const float* py = pos + (size_t)(b*3+1)*Nq;
    const float* pz = pos + (size_t)(b*3+2)*Nq;
    const float xn=px[n], yn=py[n], zn=pz[n];
    const float sqn = __fadd_rn(__fadd_rn(__fmul_rn(xn,xn),__fmul_rn(yn,yn)),__fmul_rn(zn,zn));

    double kd[32];
    #pragma unroll
    for (int i=0;i<32;i++){
      int j = i*64 + lane;
      float x=px[j], y=py[j], z=pz[j];
      float sqj = __fadd_rn(__fadd_rn(__fmul_rn(x,x),__fmul_rn(y,y)),__fmul_rn(z,z));
      float dot = __fadd_rn(__fadd_rn(__fmul_rn(xn,x),__fmul_rn(yn,y)),__fmul_rn(zn,z));
      float d   = __fsub_rn(__fadd_rn(sqn,sqj), __fmul_rn(2.0f,dot));
      unsigned u = __float_as_uint(d);
      u ^= ((unsigned)((int)u >> 31)) | 0x80000000u;
      kd[i] = (double)u * 2048.0 + (double)j;
    }

    const double BIG = 9.0e15;
    // ---- build per-lane sorted top-4 buffer (b0<=b1<=b2<=b3) ----
    double b0=BIG, b1=BIG, b2=BIG, b3=BIG;
    #pragma unroll
    for (int i=0;i<32;i++){
      double x = kd[i];
      double M0 = fmax(b0, x);  b0 = fmin(b0, x);
      double M1 = fmax(b1, M0); b1 = fmin(b1, M0);
      double M2 = fmax(b2, M1); b2 = fmin(b2, M1);
      b3 = fmin(b3, M2);
    }

    double lane_last = -1.0;
    int cnt = 0;
    for (int s=0;s<KNNq;s++){
      // global min of buffer heads
      double m = b0;
      #pragma unroll
      for (int off=1; off<64; off<<=1)
        m = fmin(m, __shfl_xor(m, off));
      if (lane == 0){
        unsigned long long kk = (unsigned long long)m;
        idxT[(size_t)pid*KNNq + s] = (int)(kk & 2047ull);
      }
      // owner pops (keys unique -> exactly one lane)
      if (b0 == m){
        lane_last = b0;
        b0 = b1; b1 = b2; b2 = b3; b3 = BIG;
        cnt++;
      }
      // rare refill: lane exhausted its 4-buffer
      if (__any(cnt >= 4)){
        if (cnt >= 4){
          b0 = BIG; b1 = BIG; b2 = BIG; b3 = BIG;
          #pragma unroll
          for (int i=0;i<32;i++){
            double x = (kd[i] > lane_last) ? kd[i] : BIG;
            double M0 = fmax(b0, x);  b0 = fmin(b0, x);
            double M1 = fmax(b1, M0); b1 = fmin(b1, M0);
            double M2 = fmax(b2, M1); b2 = fmin(b2, M1);
            b3 = fmin(b3, M2);
          }
          cnt = 0;
        }
      }
    }
  }
}

// ---------------------------------------------------------------------------
// Kernel 3: fused attn, P=2 points per block.
// Round-9: stage-4 MFMA operands SWAPPED (acc = mfma(sT_frag, ctwT_frag)):
// output now has col(lane&15)=t_out, row(reg)=pk -> the 20-neighbor softmax
// reduction axis is REGISTER-LOCAL (12 pk per lane, f32, no bf16 round-trip).
// Softmax done in-register with cross-quad shfl_xor(16/32) reduces; the
// (nt,quad) groups are uniformly p0/p1/invalid so masking is ~4 selects/jm.
// Deletes: ctS LDS round-trip (48 cvt + 48 st + 40 ld + 40 b2f per thread),
// barriers B7+B8 (9 -> 7). LDS 40,448 -> 30,976 B. Occupancy stays 4 blocks/CU
// (register-capped per round-7 lesson; keep __launch_bounds__(256,4)).
// ---------------------------------------------------------------------------
#define UADDR(row, colb) ((((row)*128 + (colb)) ^ (((row)&7)<<4)))
#define SADDR(row, colb) ((((row)*256 + (colb)) ^ (((row)&7)<<4)))

__global__ __launch_bounds__(256, 4) void k_attn(
  const float* __restrict__ pos,
  const float* __restrict__ valueT, const short* __restrict__ kfT,
  const short* __restrict__ qfT,    const short* __restrict__ vfT,
  const int* __restrict__ idxT,
  const float* __restrict__ pw1, const float* __restrict__ pb1,
  const float* __restrict__ pg,  const float* __restrict__ pbt,
  const float* __restrict__ prm, const float* __restrict__ prv,
  const short* __restrict__ pw2b, const float* __restrict__ pb2,
  const short* __restrict__ aw1b, const float* __restrict__ ab1,
  const float* __restrict__ ag,  const float* __restrict__ abt,
  const float* __restrict__ arm, const float* __restrict__ arv,
  const short* __restrict__ ctwT,
  const short* __restrict__ web,  const float* __restrict__ be,
  float* __restrict__ out)
{
  // unionA: sT(48x256B swz) [0,12288) | sh2S [12288,13312)
  __shared__ __align__(16) char unionA[13312];
  // unionB: hB(48x128B swz) -> aggB(rows 0..7, swz)
  __shared__ __align__(16) char unionB[6144];
  // unionC: init: prl(3x48 f32)+nb(48 int) ; stage2+: uT(48x128B swz)
  __shared__ __align__(16) char unionC[6144];
  __shared__ __align__(16) short vgB[64*42];   // [o][p*20+k], stride 42 (odd dwords)

  float* sh2S = (float*)(unionA + 12288);
  float* prl  = (float*)unionC;
  int*   nb   = (int*)(unionC + 576);

  const int t = threadIdx.x;
  const int b  = blockIdx.x >> 10;
  const int n0 = (blockIdx.x & 1023) * 2;
  const int lane = t & 63, quad = lane >> 4, l15 = lane & 15, w = t >> 6;
  const size_t bN = (size_t)b * Nq;
  const int obase = w*16 + quad*4;

  if (t < 48){
    int p = (t >= 24);
    int k = t - p*24;
    int nn = n0 + p;
    int j = (k < KNNq) ? idxT[(bN + nn)*KNNq + k] : nn;
    nb[t] = j;
    #pragma unroll
    for (int d=0; d<3; d++){
      prl[d*48+t] = pos[((size_t)(b*3+d))*Nq + nn] - pos[((size_t)(b*3+d))*Nq + j];
    }
  }
  {
    float sc = ag[t] * rsqrtf(arv[t] + 1e-5f);
    sh2S[t]  = ab1[t]*sc + (abt[t] - arm[t]*sc);
  }
  __syncthreads();                               // B1

  // ---- prefetch q/k/v fragments (consumed in stage-2 epilogue) ----
  short4v pq4[3], pk4[3], pv4[3];
  #pragma unroll
  for (int nt=0; nt<3; nt++){
    int pk = nt*16 + l15;
    int p  = (pk >= 24);
    int j  = nb[pk];
    pq4[nt] = *reinterpret_cast<const short4v*>(qfT + (bN + n0 + p)*Dq + obase);
    pk4[nt] = *reinterpret_cast<const short4v*>(kfT + (bN + j)*Dq + obase);
    pv4[nt] = *reinterpret_cast<const short4v*>(vfT + (bN + j)*Dq + obase);
  }

  // ---- stage 1: pos_mlp hidden -> hB (BN folded into weights here) ----
  {
    const int ph = t & 63;
    float sc = pg[ph] * rsqrtf(prv[ph] + 1e-5f);
    float w0 = pw1[ph*3+0]*sc, w1 = pw1[ph*3+1]*sc, w2 = pw1[ph*3+2]*sc;
    float bb = pb1[ph]*sc + (pbt[ph] - prm[ph]*sc);
    #pragma unroll
    for (int m=0;m<12;m++){
      int pk = w + m*4;
      float h = fmaf(w0, prl[pk], fmaf(w1, prl[48+pk], fmaf(w2, prl[96+pk], bb)));
      *(short*)(unionB + UADDR(pk, ph*2)) = (short)f2b(fmaxf(h, 0.f));
    }
  }
  __syncthreads();                               // B2

  // ---- stage 2: pos_emb via MFMA; epilogue builds uT, vgB ----
  {
    f32x4 accP[3];
    #pragma unroll
    for (int nt=0;nt<3;nt++) accP[nt]=(f32x4)0.f;
    #pragma unroll
    for (int ks=0;ks<2;ks++){
      const int kcolb = (ks*32 + quad*8)*2;
      short8 a = *reinterpret_cast<const short8*>(pw2b + ((w*2+ks)*64 + lane)*8);
      #pragma unroll
      for (int nt=0;nt<3;nt++){
        short8 bb = *reinterpret_cast<const short8*>(unionB + UADDR(nt*16+l15, kcolb));
        accP[nt] = __builtin_amdgcn_mfma_f32_16x16x32_bf16(a, bb, accP[nt], 0,0,0);
      }
    }
    #pragma unroll
    for (int nt=0;nt<3;nt++){
      int pk = nt*16 + l15;
      bool vld = (pk < 20) || (pk >= 24 && pk < 44);
      int col  = pk - (pk >= 24 ? 4 : 0);
      short4v ut4;
      #pragma unroll
      for (int r=0;r<4;r++){
        int o = obase + r;
        float pe = accP[nt][r] + pb2[o];
        ut4[r] = (short)f2b((b2f(pq4[nt][r]) - b2f(pk4[nt][r])) + pe);
        if (vld) vgB[o*42 + col] = (short)f2b(b2f(pv4[nt][r]) + pe);
      }
      *(short4v*)(unionC + UADDR(pk, obase*2)) = ut4;
    }
  }
  __syncthreads();                               // B3 (hB dead, prl/nb dead)

  // ---- stages 3+4 chunked over hidden cols (2 x 128); accT spans chunks ----
  // stage-4 operands SWAPPED: accT[jm][nt][r] = ct[pk=nt*16+quad*4+r][t_out=(w*4+jm)*16+l15]
  f32x4 accT[4][3];
  #pragma unroll
  for (int jm=0;jm<4;jm++)
    #pragma unroll
    for (int nt=0;nt<3;nt++) accT[jm][nt]=(f32x4)0.f;

  #pragma unroll
  for (int ch=0; ch<2; ch++){
    // stage 3 partial: hidden cols [ch*128, ch*128+128)
    f32x4 accC[2][3];
    #pragma unroll
    for (int jm=0;jm<2;jm++)
      #pragma unroll
      for (int nt=0;nt<3;nt++) accC[jm][nt]=(f32x4)0.f;
    __builtin_amdgcn_s_setprio(1);
    #pragma unroll
    for (int ks=0;ks<2;ks++){
      const int kcolb = (ks*32 + quad*8)*2;
      short8 bb[3];
      #pragma unroll
      for (int nt=0;nt<3;nt++)
        bb[nt] = *reinterpret_cast<const short8*>(unionC + UADDR(nt*16+l15, kcolb));
      #pragma unroll
      for (int jm=0;jm<2;jm++){
        int mt = ch*8 + w*2 + jm;
        short8 a = *reinterpret_cast<const short8*>(aw1b + ((mt*2+ks)*64 + lane)*8);
        #pragma unroll
        for (int nt=0;nt<3;nt++)
          accC[jm][nt] = __builtin_amdgcn_mfma_f32_16x16x32_bf16(a, bb[nt], accC[jm][nt], 0,0,0);
      }
    }
    __builtin_amdgcn_s_setprio(0);

    // T14: prefetch stage-4 ksl=0 A-frags (static L2 addrs) before the barrier
    short8 actw0[4];
    #pragma unroll
    for (int jm=0;jm<4;jm++)
      actw0[jm] = *reinterpret_cast<const short8*>(ctwT + (((w*4+jm)*8 + ch*4)*64 + lane)*8);

    if (ch == 1) __syncthreads();                // B5: stage4-c0 done reading sT
    #pragma unroll
    for (int jm=0;jm<2;jm++){
      const int colb = ((w*2+jm)*16 + quad*4)*2;
      #pragma unroll
      for (int nt=0;nt<3;nt++){
        int pk = nt*16 + l15;
        short4v pkv;
        #pragma unroll
        for (int r=0;r<4;r++){
          int c = ch*128 + (w*2+jm)*16 + quad*4 + r;
          pkv[r] = (short)f2b(fmaxf(accC[jm][nt][r] + sh2S[c], 0.f));
        }
        *(short4v*)(unionA + SADDR(pk, colb)) = pkv;
      }
    }
    __syncthreads();                             // B4 / B6: sT chunk visible
    __builtin_amdgcn_s_setprio(1);
    #pragma unroll
    for (int ksl=0; ksl<4; ksl++){
      const int kcolb = (ksl*32 + quad*8)*2;
      short8 bb[3];
      #pragma unroll
      for (int nt=0;nt<3;nt++)
        bb[nt] = *reinterpret_cast<const short8*>(unionA + SADDR(nt*16+l15, kcolb));
      #pragma unroll
      for (int jm=0;jm<4;jm++){
        int mt = w*4 + jm;
        short8 a = (ksl == 0) ? actw0[jm]
                 : *reinterpret_cast<const short8*>(ctwT + ((mt*8 + ch*4 + ksl)*64 + lane)*8);
        // SWAPPED: A = sT fragment (rows = pk), B = ctwT bytes (delivers W^T)
        #pragma unroll
        for (int nt=0;nt<3;nt++)
          accT[jm][nt] = __builtin_amdgcn_mfma_f32_16x16x32_bf16(bb[nt], a, accT[jm][nt], 0,0,0);
      }
    }
    __builtin_amdgcn_s_setprio(0);
  }
  // NOTE: no barrier here — softmax uses only accT (registers) and vgB
  // (stable since B3). Barriers B7/B8 of the old ctS round-trip are gone.

  // ---- prefetch identity + web frags for stage 5 (T14) ----
  float4 idv[4];
  if (l15 < 8){
    int p = l15 >> 2;
    #pragma unroll
    for (int jm=0;jm<4;jm++)
      idv[jm] = *reinterpret_cast<const float4*>(valueT + (bN + n0 + p)*Cq + (w*4+jm)*16 + quad*4);
  }
  short8 aweb[2][4];
  #pragma unroll
  for (int ks=0;ks<2;ks++)
    #pragma unroll
    for (int jm=0;jm<4;jm++)
      aweb[ks][jm] = *reinterpret_cast<const short8*>(web + (((w*4+jm)*2+ks)*64 + lane)*8);

  // ---- in-register softmax over pk + PV aggregate -> aggB ----
  // lane's 12 pk per jm: nt0 -> pk 0..15 (p0); nt1 -> quad0: pk16-19 (p0),
  // quad1: pad, quad>=2: pk24-31 (p1); nt2 -> quad<=2: pk32-43 (p1), quad3: pad.
  {
    #pragma unroll
    for (int jm=0;jm<4;jm++){
      float m0 = -1e30f, m1 = -1e30f;
      #pragma unroll
      for (int r=0;r<4;r++) m0 = fmaxf(m0, accT[jm][0][r]);
      float g1 = fmaxf(fmaxf(accT[jm][1][0],accT[jm][1][1]),
                       fmaxf(accT[jm][1][2],accT[jm][1][3]));
      float g2 = fmaxf(fmaxf(accT[jm][2][0],accT[jm][2][1]),
                       fmaxf(accT[jm][2][2],accT[jm][2][3]));
      if (quad == 0) m0 = fmaxf(m0, g1);
      if (quad >= 2) m1 = fmaxf(m1, g1);
      if (quad <= 2) m1 = fmaxf(m1, g2);
      m0 = fmaxf(m0, __shfl_xor(m0, 16)); m0 = fmaxf(m0, __shfl_xor(m0, 32));
      m1 = fmaxf(m1, __shfl_xor(m1, 16)); m1 = fmaxf(m1, __shfl_xor(m1, 32));

      const int o = (w*4+jm)*4 + (l15 >> 2);   // = t_out >> 2
      float s0 = 0.f, s1 = 0.f, pv0 = 0.f, pv1 = 0.f;
      #pragma unroll
      for (int r=0;r<4;r++){
        float e = __expf(accT[jm][0][r] - m0);
        s0 += e;
        pv0 = fmaf(e, b2f(vgB[o*42 + quad*4 + r]), pv0);
      }
      #pragma unroll
      for (int r=0;r<4;r++){
        bool isp0 = (quad == 0), vld = (quad != 1);
        float mm = isp0 ? m0 : m1;
        float e  = vld ? __expf(accT[jm][1][r] - mm) : 0.f;
        int col  = isp0 ? (16 + r) : (vld ? (12 + quad*4 + r) : 0); // p1: 20+(quad*4+r-8)
        float vg = b2f(vgB[o*42 + col]);
        if (isp0){ s0 += e; pv0 = fmaf(e, vg, pv0); }
        else     { s1 += e; pv1 = fmaf(e, vg, pv1); }
      }
      #pragma unroll
      for (int r=0;r<4;r++){
        bool vld = (quad <= 2);
        float e = vld ? __expf(accT[jm][2][r] - m1) : 0.f;
        int col = vld ? (28 + quad*4 + r) : 0;
        s1 += e;
        pv1 = fmaf(e, b2f(vgB[o*42 + col]), pv1);
      }
      s0  += __shfl_xor(s0, 16);  s0  += __shfl_xor(s0, 32);
      s1  += __shfl_xor(s1, 16);  s1  += __shfl_xor(s1, 32);
      pv0 += __shfl_xor(pv0, 16); pv0 += __shfl_xor(pv0, 32);
      pv1 += __shfl_xor(pv1, 16); pv1 += __shfl_xor(pv1, 32);
      if (quad == 0){
        int rr = l15 & 3;
        *(short*)(unionB + UADDR(rr,     o*2)) = (short)f2b(__fdividef(pv0, s0));
        *(short*)(unionB + UADDR(4 + rr, o*2)) = (short)f2b(__fdividef(pv1, s1));
      }
    }
  }
  __syncthreads();                               // B7': aggB ready

  // ---- stage 5: conv_end (64->256) MFMA + bias + identity ----
  {
    f32x4 accE[4];
    #pragma unroll
    for (int jm=0;jm<4;jm++) accE[jm]=(f32x4)0.f;
    __builtin_amdgcn_s_setprio(1);
    #pragma unroll
    for (int ks=0;ks<2;ks++){
      const int kcolb = (ks*32 + quad*8)*2;
      short8 bb = *reinterpret_cast<const short8*>(unionB + UADDR(l15, kcolb));
      #pragma unroll
      for (int jm=0;jm<4;jm++){
        accE[jm] = __builtin_amdgcn_mfma_f32_16x16x32_bf16(aweb[ks][jm], bb, accE[jm], 0,0,0);
      }
    }
    __builtin_amdgcn_s_setprio(0);
    if (l15 < 8){
      int p = l15 >> 2, rr = l15 & 3;
      #pragma unroll
      for (int jm=0;jm<4;jm++){
        float4 b4 = *reinterpret_cast<const float4*>(be + (w*4+jm)*16 + quad*4);
        #pragma unroll
        for (int r=0;r<4;r++){
          int c = (w*4+jm)*16 + quad*4 + r;
          float y = accE[jm][r] + ((const float*)&b4)[r] + ((const float*)&idv[jm])[r];
          out[((size_t)(b*Cq+c))*((size_t)Nq*UPq) + (size_t)(n0+p)*UPq + rr] = y;
        }
      }
    }
  }
}

// ---------------------------------------------------------------------------
extern "C" void kernel_launch(void* const* d_in, const int* in_sizes, int n_in,
                              void* d_out, int out_size, void* d_ws, size_t ws_size,
                              hipStream_t stream)
{
  const float* pos  = (const float*)d_in[0];
  const float* key  = (const float*)d_in[1];
  const float* qry  = (const float*)d_in[2];
  const float* wv1  = (const float*)d_in[3];
  const float* bv1  = (const float*)d_in[4];
  const float* wv2  = (const float*)d_in[5];
  const float* bv2  = (const float*)d_in[6];
  const float* wvs  = (const float*)d_in[7];
  const float* bvs  = (const float*)d_in[8];
  const float* wk   = (const float*)d_in[9];
  const float* bk   = (const float*)d_in[10];
  const float* wq   = (const float*)d_in[11];
  const float* bq   = (const float*)d_in[12];
  const float* wval = (const float*)d_in[13];
  const float* bval = (const float*)d_in[14];
  const float* pw1  = (const float*)d_in[15];
  const float* pb1  = (const float*)d_in[16];
  const float* pg   = (const float*)d_in[17];
  const float* pbt  = (const float*)d_in[18];
  const float* prm  = (const float*)d_in[19];
  const float* prv  = (const float*)d_in[20];
  const float* pw2  = (const float*)d_in[21];
  const float* pb2  = (const float*)d_in[22];
  const float* aw1  = (const float*)d_in[23];
  const float* ab1  = (const float*)d_in[24];
  const float* ag   = (const float*)d_in[25];
  const float* abt  = (const float*)d_in[26];
  const float* arm  = (const float*)d_in[27];
  const float* arv  = (const float*)d_in[28];
  const float* ctw  = (const float*)d_in[29];
  const float* we   = (const float*)d_in[31];
  const float* be   = (const float*)d_in[32];

  char* ws = (char*)d_ws;
  float* valueT = (float*)(ws);                    // 8 MB fp32
  short* kfT    = (short*)(ws + 8388608);          // 1 MB bf16
  short* qfT    = (short*)(ws + 9437184);
  short* vfT    = (short*)(ws + 10485760);
  int*   idxT   = (int*)  (ws + 11534336);         // 640 KB
  short* aw1b   = (short*)(ws + 12189696);         // 32 KB
  short* ctwT   = (short*)(ws + 12222464);         // 128 KB
  short* wv1b   = (short*)(ws + 12353536);         // 256 KB
  short* wvsb   = (short*)(ws + 12615680);         // 256 KB
  short* wv2b   = (short*)(ws + 12877824);         // 128 KB
  short* wkb    = (short*)(ws + 13008896);         // 32 KB
  short* wqb    = (short*)(ws + 13041664);         // 32 KB
  short* wvalb  = (short*)(ws + 13074432);         // 32 KB
  short* pw2b   = (short*)(ws + 13107200);         // 8 KB
  short* web    = (short*)(ws + 13115392);         // 32 KB
  float* out    = (float*)d_out;

  k_prep<<<dim3(1872), dim3(256), 0, stream>>>(
      aw1, ctw, wv1, wvs, wv2, wk, wq, wval, pw2, we,
      aw1b, ctwT, wv1b, wvsb, wv2b, wkb, wqb, wvalb, pw2b, web,
      ag, arv);
  k_vk<<<dim3(2560), dim3(256), 0, stream>>>(
      key, qry, wv1b, wvsb, wv2b, wkb, wqb, wvalb,
      bv1, bv2, bvs, bk, bq, bval,
      valueT, kfT, qfT, vfT, pos, idxT);
  k_attn<<<dim3(Bq*Nq/2), dim3(256), 0, stream>>>(
      pos, valueT, kfT, qfT, vfT, idxT,
      pw1, pb1, pg, pbt, prm, prv, pw2b, pb2,
      aw1b, ab1, ag, abt, arm, arv, ctwT, web, be, out);
}

// Round 10
// 251.248 us; speedup vs baseline: 1.0355x; 1.0355x over previous
//
#include <hip/hip_runtime.h>
#include <hip/hip_bf16.h>

#define Bq 4
#define Nq 2048
#define Cq 256
#define Dq 64
#define UPq 4
#define KNNq 20
#define PHq 64
#define DMq 256   // D*MULT
#define PTS 16    // points per block in k_value

typedef __attribute__((ext_vector_type(8))) short short8;
typedef __attribute__((ext_vector_type(4))) short short4v;
typedef __attribute__((ext_vector_type(4))) float f32x4;
typedef __hip_bfloat16 bf16;

__device__ __forceinline__ unsigned short f2b(float x){
  bf16 h = __float2bfloat16(x);
  return *reinterpret_cast<unsigned short*>(&h);
}
__device__ __forceinline__ float b2f(short s){
  return __bfloat162float(*reinterpret_cast<bf16*>(&s));
}

// ---------------------------------------------------------------------------
// Kernel 0: weight prep — emit bf16 weights in MFMA A-fragment-swizzled order:
// dst[((mt*KS+ks)*64+lane)*8+j] = W[mt*16+(lane&15)][ks*32+(lane>>4)*8+j]
// aw1 additionally gets the attn-BN scale folded in (row scale ag*rsqrt(arv+eps)).
// ---------------------------------------------------------------------------
__device__ __forceinline__ void swz(const float* __restrict__ src,
                                    short* __restrict__ dst,
                                    int M, int K, int g, bool transp)
{
  int j = g & 7, lane = (g >> 3) & 63, rest = g >> 9;
  int KS = K >> 5;
  int ks = rest % KS, mt = rest / KS;
  int m = mt*16 + (lane & 15);
  int k = ks*32 + ((lane >> 4) << 3) + j;
  float v = transp ? src[k*M + m] : src[m*K + k];
  dst[g] = (short)f2b(v);
}

__device__ __forceinline__ void swz_s(const float* __restrict__ src,
                                      short* __restrict__ dst,
                                      int M, int K, int g,
                                      const float* __restrict__ gam,
                                      const float* __restrict__ var)
{
  int j = g & 7, lane = (g >> 3) & 63, rest = g >> 9;
  int KS = K >> 5;
  int ks = rest % KS, mt = rest / KS;
  int m = mt*16 + (lane & 15);
  int k = ks*32 + ((lane >> 4) << 3) + j;
  float sc = gam[m] * rsqrtf(var[m] + 1e-5f);
  dst[g] = (short)f2b(src[m*K + k] * sc);
}

__global__ __launch_bounds__(256) void k_prep(
    const float* __restrict__ aw1, const float* __restrict__ ctw,
    const float* __restrict__ wv1, const float* __restrict__ wvs,
    const float* __restrict__ wv2, const float* __restrict__ wk,
    const float* __restrict__ wq,  const float* __restrict__ wval,
    const float* __restrict__ pw2, const float* __restrict__ we,
    short* __restrict__ aw1b, short* __restrict__ ctwT,
    short* __restrict__ wv1b, short* __restrict__ wvsb,
    short* __restrict__ wv2b, short* __restrict__ wkb,
    short* __restrict__ wqb,  short* __restrict__ wvalb,
    short* __restrict__ pw2b, short* __restrict__ web,
    const float* __restrict__ ag, const float* __restrict__ arv)
{
  const int t = threadIdx.x, bidx = blockIdx.x;
  if (bidx < 512){
    swz(wv1, wv1b, 256, 512, bidx*256 + t, false);
  } else if (bidx < 1024){
    swz(wvs, wvsb, 256, 512, (bidx-512)*256 + t, false);
  } else if (bidx < 1280){
    swz(wv2, wv2b, 256, 256, (bidx-1024)*256 + t, false);
  } else if (bidx < 1344){
    swz(wk, wkb, 64, 256, (bidx-1280)*256 + t, false);
  } else if (bidx < 1408){
    swz(wq, wqb, 64, 256, (bidx-1344)*256 + t, false);
  } else if (bidx < 1472){
    swz(wval, wvalb, 64, 256, (bidx-1408)*256 + t, false);
  } else if (bidx < 1488){
    swz(pw2, pw2b, 64, 64, (bidx-1472)*256 + t, false);
  } else if (bidx < 1552){
    swz_s(aw1, aw1b, 256, 64, (bidx-1488)*256 + t, ag, arv);  // BN scale folded in
  } else if (bidx < 1616){
    swz(we, web, 256, 64, (bidx-1552)*256 + t, false);
  } else {
    swz(ctw, ctwT, 256, 256, (bidx-1616)*256 + t, true);  // W[m=t_out][k=c] = ctw[c][t_out]
  }
}

// ---------------------------------------------------------------------------
// Kernel 1: FUSED value-MLP + KNN ("k_vk").  (round-6 verified)
// ---------------------------------------------------------------------------
__global__ __launch_bounds__(256, 4) void k_vk(
    const float* __restrict__ key, const float* __restrict__ query,
    const short* __restrict__ wv1b, const short* __restrict__ wvsb,
    const short* __restrict__ wv2b, const short* __restrict__ wkb,
    const short* __restrict__ wqb,  const short* __restrict__ wvalb,
    const float* __restrict__ bv1, const float* __restrict__ bv2,
    const float* __restrict__ bvs, const float* __restrict__ bk,
    const float* __restrict__ bq,  const float* __restrict__ bval,
    float* __restrict__ valueT, short* __restrict__ kfT,
    short* __restrict__ qfT,    short* __restrict__ vfT,
    const float* __restrict__ pos, int* __restrict__ idxT)
{
  const int t = threadIdx.x;
  const int lane = t & 63, w = t >> 6;
  const int vb = blockIdx.x / 5, rem = blockIdx.x % 5;

  if (rem == 4){
    // ================= value path (block vb of 512) =================
    __shared__ __align__(16) short Xb[16*520];
    __shared__ __align__(16) short hidB[16*264];
    __shared__ __align__(16) short valB[16*264];
    const int b = vb >> 7;
    const int n0 = (vb & 127) * PTS;
    const int quad = lane >> 4, l15 = lane & 15;

    {
      const int c4 = t >> 2, pq = t & 3;
      #pragma unroll
      for (int pass=0; pass<4; pass++){
        int c = pass*64 + c4;
        float4 kv = *reinterpret_cast<const float4*>(key   + ((size_t)(b*Cq+c))*Nq + n0 + pq*4);
        float4 qv = *reinterpret_cast<const float4*>(query + ((size_t)(b*Cq+c))*Nq + n0 + pq*4);
        const float* kf_ = (const float*)&kv;
        const float* qf_ = (const float*)&qv;
        #pragma unroll
        for (int i=0;i<4;i++){
          Xb[(pq*4+i)*520 + c]       = (short)f2b(kf_[i]);
          Xb[(pq*4+i)*520 + 256 + c] = (short)f2b(qf_[i]);
        }
      }
    }
    __syncthreads();

    f32x4 acc1[4], accS[4];
    #pragma unroll
    for (int jm=0;jm<4;jm++){ acc1[jm]=(f32x4)0.f; accS[jm]=(f32x4)0.f; }

    #pragma unroll
    for (int ks=0;ks<16;ks++){
      const int kcol = ks*32 + quad*8;
      short8 xb = *reinterpret_cast<const short8*>(&Xb[l15*520 + kcol]);
      #pragma unroll
      for (int jm=0;jm<4;jm++){
        int mt = w*4 + jm;
        short8 a1 = *reinterpret_cast<const short8*>(wv1b + ((mt*16+ks)*64 + lane)*8);
        short8 as = *reinterpret_cast<const short8*>(wvsb + ((mt*16+ks)*64 + lane)*8);
        acc1[jm] = __builtin_amdgcn_mfma_f32_16x16x32_bf16(a1, xb, acc1[jm], 0,0,0);
        accS[jm] = __builtin_amdgcn_mfma_f32_16x16x32_bf16(as, xb, accS[jm], 0,0,0);
      }
    }
    #pragma unroll
    for (int jm=0;jm<4;jm++){
      #pragma unroll
      for (int r=0;r<4;r++){
        int h = (w*4+jm)*16 + quad*4 + r;
        hidB[l15*264 + h] = (short)f2b(fmaxf(acc1[jm][r] + bv1[h], 0.f));
      }
    }
    __syncthreads();

    #pragma unroll
    for (int ks=0;ks<8;ks++){
      const int kcol = ks*32 + quad*8;
      short8 hb = *reinterpret_cast<const short8*>(&hidB[l15*264 + kcol]);
      #pragma unroll
      for (int jm=0;jm<4;jm++){
        int mt = w*4 + jm;
        short8 a = *reinterpret_cast<const short8*>(wv2b + ((mt*8+ks)*64 + lane)*8);
        accS[jm] = __builtin_amdgcn_mfma_f32_16x16x32_bf16(a, hb, accS[jm], 0,0,0);
      }
    }
    #pragma unroll
    for (int jm=0;jm<4;jm++){
      const int cb = (w*4+jm)*16 + quad*4;
      float4 v4;
      #pragma unroll
      for (int r=0;r<4;r++){
        int c = cb + r;
        float v = accS[jm][r] + bv2[c] + bvs[c];
        ((float*)&v4)[r] = v;
        valB[l15*264 + c] = (short)f2b(v);
      }
      // direct fp32 write of value (identity path), 16B contiguous
      *reinterpret_cast<float4*>(valueT + ((size_t)(b*Nq + n0 + l15))*Cq + cb) = v4;
    }
    __syncthreads();

    {
      f32x4 pk4=(f32x4)0.f, pq4=(f32x4)0.f, pv4=(f32x4)0.f;
      #pragma unroll
      for (int ks=0;ks<8;ks++){
        const int kcol = ks*32 + quad*8;
        short8 xk = *reinterpret_cast<const short8*>(&Xb[l15*520 + kcol]);
        short8 xq = *reinterpret_cast<const short8*>(&Xb[l15*520 + 256 + kcol]);
        short8 xv = *reinterpret_cast<const short8*>(&valB[l15*264 + kcol]);
        short8 ak = *reinterpret_cast<const short8*>(wkb  + ((w*8+ks)*64 + lane)*8);
        short8 aq = *reinterpret_cast<const short8*>(wqb  + ((w*8+ks)*64 + lane)*8);
        short8 av = *reinterpret_cast<const short8*>(wvalb+ ((w*8+ks)*64 + lane)*8);
        pk4 = __builtin_amdgcn_mfma_f32_16x16x32_bf16(ak, xk, pk4, 0,0,0);
        pq4 = __builtin_amdgcn_mfma_f32_16x16x32_bf16(aq, xq, pq4, 0,0,0);
        pv4 = __builtin_amdgcn_mfma_f32_16x16x32_bf16(av, xv, pv4, 0,0,0);
      }
      short4v ok, oq, ov;
      #pragma unroll
      for (int r=0;r<4;r++){
        int o = w*16 + quad*4 + r;
        ok[r] = (short)f2b(pk4[r] + bk[o]);
        oq[r] = (short)f2b(pq4[r] + bq[o]);
        ov[r] = (short)f2b(pv4[r] + bval[o]);
      }
      int n = n0 + l15;
      size_t base = ((size_t)(b*Nq+n))*Dq + w*16 + quad*4;
      *reinterpret_cast<short4v*>(kfT + base) = ok;
      *reinterpret_cast<short4v*>(qfT + base) = oq;
      *reinterpret_cast<short4v*>(vfT + base) = ov;
    }
  } else {
    // ================= knn path (block kb of 2048) =================
    const int kb = vb*4 + rem;
    const int pid = kb*4 + w;
    const int b = pid >> 11;
    const int n = pid & (Nq-1);
    const float* px = pos + (size_t)(b*3+0)*Nq;
    const float* py = pos + (size_t)(b*3+1)*Nq;
    const float* pz = pos + (size_t)(b*3+2)*Nq;
    const float xn=px[n], yn=py[n], zn=pz[n];
    const float sqn = __fadd_rn(__fadd_rn(__fmul_rn(xn,xn),__fmul_rn(yn,yn)),__fmul_rn(zn,zn));

    double kd[32];
    #pragma unroll
    for (int i=0;i<32;i++){
      int j = i*64 + lane;
      float x=px[j], y=py[j], z=pz[j];
      float sqj = __fadd_rn(__fadd_rn(__fmul_rn(x,x),__fmul_rn(y,y)),__fmul_rn(z,z));
      float dot = __fadd_rn(__fadd_rn(__fmul_rn(xn,x),__fmul_rn(yn,y)),__fmul_rn(zn,z));
      float d   = __fsub_rn(__fadd_rn(sqn,sqj), __fmul_rn(2.0f,dot));
      unsigned u = __float_as_uint(d);
      u ^= ((unsigned)((int)u >> 31)) | 0x80000000u;
      kd[i] = (double)u * 2048.0 + (double)j;
    }

    const double BIG = 9.0e15;
    // ---- build per-lane sorted top-4 buffer (b0<=b1<=b2<=b3) ----
    double b0=BIG, b1=BIG, b2=BIG, b3=BIG;
    #pragma unroll
    for (int i=0;i<32;i++){
      double x = kd[i];
      double M0 = fmax(b0, x);  b0 = fmin(b0, x);
      double M1 = fmax(b1, M0); b1 = fmin(b1, M0);
      double M2 = fmax(b2, M1); b2 = fmin(b2, M1);
      b3 = fmin(b3, M2);
    }

    double lane_last = -1.0;
    int cnt = 0;
    for (int s=0;s<KNNq;s++){
      // global min of buffer heads
      double m = b0;
      #pragma unroll
      for (int off=1; off<64; off<<=1)
        m = fmin(m, __shfl_xor(m, off));
      if (lane == 0){
        unsigned long long kk = (unsigned long long)m;
        idxT[(size_t)pid*KNNq + s] = (int)(kk & 2047ull);
      }
      // owner pops (keys unique -> exactly one lane)
      if (b0 == m){
        lane_last = b0;
        b0 = b1; b1 = b2; b2 = b3; b3 = BIG;
        cnt++;
      }
      // rare refill: lane exhausted its 4-buffer
      if (__any(cnt >= 4)){
        if (cnt >= 4){
          b0 = BIG; b1 = BIG; b2 = BIG; b3 = BIG;
          #pragma unroll
          for (int i=0;i<32;i++){
            double x = (kd[i] > lane_last) ? kd[i] : BIG;
            double M0 = fmax(b0, x);  b0 = fmin(b0, x);
            double M1 = fmax(b1, M0); b1 = fmin(b1, M0);
            double M2 = fmax(b2, M1); b2 = fmin(b2, M1);
            b3 = fmin(b3, M2);
          }
          cnt = 0;
        }
      }
    }
  }
}

// ---------------------------------------------------------------------------
// Kernel 3: fused attn, P=2 points per block.
// Round-10: round-9's in-register softmax (operand-swapped stage 4) KEPT,
// but the idv/aweb T14 prefetches are MOVED to after softmax's last accT
// read (accT dead) — round 9 issued them while accT (48 regs) was live,
// blowing the ~128-reg unified budget -> 40 MB/dispatch scratch spill
// (FETCH 18.5->30.5, WRITE 41->69.6). Prefetches now sit between softmax
// and the B7' barrier, still ahead of stage-5 consumption.
// LDS 30,976 B; 7 barriers; __launch_bounds__(256,4) (register-capped).
// ---------------------------------------------------------------------------
#define UADDR(row, colb) ((((row)*128 + (colb)) ^ (((row)&7)<<4)))
#define SADDR(row, colb) ((((row)*256 + (colb)) ^ (((row)&7)<<4)))

__global__ __launch_bounds__(256, 4) void k_attn(
  const float* __restrict__ pos,
  const float* __restrict__ valueT, const short* __restrict__ kfT,
  const short* __restrict__ qfT,    const short* __restrict__ vfT,
  const int* __restrict__ idxT,
  const float* __restrict__ pw1, const float* __restrict__ pb1,
  const float* __restrict__ pg,  const float* __restrict__ pbt,
  const float* __restrict__ prm, const float* __restrict__ prv,
  const short* __restrict__ pw2b, const float* __restrict__ pb2,
  const short* __restrict__ aw1b, const float* __restrict__ ab1,
  const float* __restrict__ ag,  const float* __restrict__ abt,
  const float* __restrict__ arm, const float* __restrict__ arv,
  const short* __restrict__ ctwT,
  const short* __restrict__ web,  const float* __restrict__ be,
  float* __restrict__ out)
{
  // unionA: sT(48x256B swz) [0,12288) | sh2S [12288,13312)
  __shared__ __align__(16) char unionA[13312];
  // unionB: hB(48x128B swz) -> aggB(rows 0..7, swz)
  __shared__ __align__(16) char unionB[6144];
  // unionC: init: prl(3x48 f32)+nb(48 int) ; stage2+: uT(48x128B swz)
  __shared__ __align__(16) char unionC[6144];
  __shared__ __align__(16) short vgB[64*42];   // [o][p*20+k], stride 42 (odd dwords)

  float* sh2S = (float*)(unionA + 12288);
  float* prl  = (float*)unionC;
  int*   nb   = (int*)(unionC + 576);

  const int t = threadIdx.x;
  const int b  = blockIdx.x >> 10;
  const int n0 = (blockIdx.x & 1023) * 2;
  const int lane = t & 63, quad = lane >> 4, l15 = lane & 15, w = t >> 6;
  const size_t bN = (size_t)b * Nq;
  const int obase = w*16 + quad*4;

  if (t < 48){
    int p = (t >= 24);
    int k = t - p*24;
    int nn = n0 + p;
    int j = (k < KNNq) ? idxT[(bN + nn)*KNNq + k] : nn;
    nb[t] = j;
    #pragma unroll
    for (int d=0; d<3; d++){
      prl[d*48+t] = pos[((size_t)(b*3+d))*Nq + nn] - pos[((size_t)(b*3+d))*Nq + j];
    }
  }
  {
    float sc = ag[t] * rsqrtf(arv[t] + 1e-5f);
    sh2S[t]  = ab1[t]*sc + (abt[t] - arm[t]*sc);
  }
  __syncthreads();                               // B1

  // ---- prefetch q/k/v fragments (consumed in stage-2 epilogue) ----
  short4v pq4[3], pk4[3], pv4[3];
  #pragma unroll
  for (int nt=0; nt<3; nt++){
    int pk = nt*16 + l15;
    int p  = (pk >= 24);
    int j  = nb[pk];
    pq4[nt] = *reinterpret_cast<const short4v*>(qfT + (bN + n0 + p)*Dq + obase);
    pk4[nt] = *reinterpret_cast<const short4v*>(kfT + (bN + j)*Dq + obase);
    pv4[nt] = *reinterpret_cast<const short4v*>(vfT + (bN + j)*Dq + obase);
  }

  // ---- stage 1: pos_mlp hidden -> hB (BN folded into weights here) ----
  {
    const int ph = t & 63;
    float sc = pg[ph] * rsqrtf(prv[ph] + 1e-5f);
    float w0 = pw1[ph*3+0]*sc, w1 = pw1[ph*3+1]*sc, w2 = pw1[ph*3+2]*sc;
    float bb = pb1[ph]*sc + (pbt[ph] - prm[ph]*sc);
    #pragma unroll
    for (int m=0;m<12;m++){
      int pk = w + m*4;
      float h = fmaf(w0, prl[pk], fmaf(w1, prl[48+pk], fmaf(w2, prl[96+pk], bb)));
      *(short*)(unionB + UADDR(pk, ph*2)) = (short)f2b(fmaxf(h, 0.f));
    }
  }
  __syncthreads();                               // B2

  // ---- stage 2: pos_emb via MFMA; epilogue builds uT, vgB ----
  {
    f32x4 accP[3];
    #pragma unroll
    for (int nt=0;nt<3;nt++) accP[nt]=(f32x4)0.f;
    #pragma unroll
    for (int ks=0;ks<2;ks++){
      const int kcolb = (ks*32 + quad*8)*2;
      short8 a = *reinterpret_cast<const short8*>(pw2b + ((w*2+ks)*64 + lane)*8);
      #pragma unroll
      for (int nt=0;nt<3;nt++){
        short8 bb = *reinterpret_cast<const short8*>(unionB + UADDR(nt*16+l15, kcolb));
        accP[nt] = __builtin_amdgcn_mfma_f32_16x16x32_bf16(a, bb, accP[nt], 0,0,0);
      }
    }
    #pragma unroll
    for (int nt=0;nt<3;nt++){
      int pk = nt*16 + l15;
      bool vld = (pk < 20) || (pk >= 24 && pk < 44);
      int col  = pk - (pk >= 24 ? 4 : 0);
      short4v ut4;
      #pragma unroll
      for (int r=0;r<4;r++){
        int o = obase + r;
        float pe = accP[nt][r] + pb2[o];
        ut4[r] = (short)f2b((b2f(pq4[nt][r]) - b2f(pk4[nt][r])) + pe);
        if (vld) vgB[o*42 + col] = (short)f2b(b2f(pv4[nt][r]) + pe);
      }
      *(short4v*)(unionC + UADDR(pk, obase*2)) = ut4;
    }
  }
  __syncthreads();                               // B3 (hB dead, prl/nb dead)

  // ---- stages 3+4 chunked over hidden cols (2 x 128); accT spans chunks ----
  // stage-4 operands SWAPPED: accT[jm][nt][r] = ct[pk=nt*16+quad*4+r][t_out=(w*4+jm)*16+l15]
  f32x4 accT[4][3];
  #pragma unroll
  for (int jm=0;jm<4;jm++)
    #pragma unroll
    for (int nt=0;nt<3;nt++) accT[jm][nt]=(f32x4)0.f;

  #pragma unroll
  for (int ch=0; ch<2; ch++){
    // stage 3 partial: hidden cols [ch*128, ch*128+128)
    f32x4 accC[2][3];
    #pragma unroll
    for (int jm=0;jm<2;jm++)
      #pragma unroll
      for (int nt=0;nt<3;nt++) accC[jm][nt]=(f32x4)0.f;
    __builtin_amdgcn_s_setprio(1);
    #pragma unroll
    for (int ks=0;ks<2;ks++){
      const int kcolb = (ks*32 + quad*8)*2;
      short8 bb[3];
      #pragma unroll
      for (int nt=0;nt<3;nt++)
        bb[nt] = *reinterpret_cast<const short8*>(unionC + UADDR(nt*16+l15, kcolb));
      #pragma unroll
      for (int jm=0;jm<2;jm++){
        int mt = ch*8 + w*2 + jm;
        short8 a = *reinterpret_cast<const short8*>(aw1b + ((mt*2+ks)*64 + lane)*8);
        #pragma unroll
        for (int nt=0;nt<3;nt++)
          accC[jm][nt] = __builtin_amdgcn_mfma_f32_16x16x32_bf16(a, bb[nt], accC[jm][nt], 0,0,0);
      }
    }
    __builtin_amdgcn_s_setprio(0);

    // T14: prefetch stage-4 ksl=0 A-frags (static L2 addrs) before the barrier
    short8 actw0[4];
    #pragma unroll
    for (int jm=0;jm<4;jm++)
      actw0[jm] = *reinterpret_cast<const short8*>(ctwT + (((w*4+jm)*8 + ch*4)*64 + lane)*8);

    if (ch == 1) __syncthreads();                // B5: stage4-c0 done reading sT
    #pragma unroll
    for (int jm=0;jm<2;jm++){
      const int colb = ((w*2+jm)*16 + quad*4)*2;
      #pragma unroll
      for (int nt=0;nt<3;nt++){
        int pk = nt*16 + l15;
        short4v pkv;
        #pragma unroll
        for (int r=0;r<4;r++){
          int c = ch*128 + (w*2+jm)*16 + quad*4 + r;
          pkv[r] = (short)f2b(fmaxf(accC[jm][nt][r] + sh2S[c], 0.f));
        }
        *(short4v*)(unionA + SADDR(pk, colb)) = pkv;
      }
    }
    __syncthreads();                             // B4 / B6: sT chunk visible
    __builtin_amdgcn_s_setprio(1);
    #pragma unroll
    for (int ksl=0; ksl<4; ksl++){
      const int kcolb = (ksl*32 + quad*8)*2;
      short8 bb[3];
      #pragma unroll
      for (int nt=0;nt<3;nt++)
        bb[nt] = *reinterpret_cast<const short8*>(unionA + SADDR(nt*16+l15, kcolb));
      #pragma unroll
      for (int jm=0;jm<4;jm++){
        int mt = w*4 + jm;
        short8 a = (ksl == 0) ? actw0[jm]
                 : *reinterpret_cast<const short8*>(ctwT + ((mt*8 + ch*4 + ksl)*64 + lane)*8);
        // SWAPPED: A = sT fragment (rows = pk), B = ctwT bytes (delivers W^T)
        #pragma unroll
        for (int nt=0;nt<3;nt++)
          accT[jm][nt] = __builtin_amdgcn_mfma_f32_16x16x32_bf16(bb[nt], a, accT[jm][nt], 0,0,0);
      }
    }
    __builtin_amdgcn_s_setprio(0);
  }
  // NOTE: no barrier here — softmax uses only accT (registers) and vgB
  // (stable since B3).

  // ---- in-register softmax over pk + PV aggregate -> aggB ----
  // lane's 12 pk per jm: nt0 -> pk 0..15 (p0); nt1 -> quad0: pk16-19 (p0),
  // quad1: pad, quad>=2: pk24-31 (p1); nt2 -> quad<=2: pk32-43 (p1), quad3: pad.
  {
    #pragma unroll
    for (int jm=0;jm<4;jm++){
      float m0 = -1e30f, m1 = -1e30f;
      #pragma unroll
      for (int r=0;r<4;r++) m0 = fmaxf(m0, accT[jm][0][r]);
      float g1 = fmaxf(fmaxf(accT[jm][1][0],accT[jm][1][1]),
                       fmaxf(accT[jm][1][2],accT[jm][1][3]));
      float g2 = fmaxf(fmaxf(accT[jm][2][0],accT[jm][2][1]),
                       fmaxf(accT[jm][2][2],accT[jm][2][3]));
      if (quad == 0) m0 = fmaxf(m0, g1);
      if (quad >= 2) m1 = fmaxf(m1, g1);
      if (quad <= 2) m1 = fmaxf(m1, g2);
      m0 = fmaxf(m0, __shfl_xor(m0, 16)); m0 = fmaxf(m0, __shfl_xor(m0, 32));
      m1 = fmaxf(m1, __shfl_xor(m1, 16)); m1 = fmaxf(m1, __shfl_xor(m1, 32));

      const int o = (w*4+jm)*4 + (l15 >> 2);   // = t_out >> 2
      float s0 = 0.f, s1 = 0.f, pv0 = 0.f, pv1 = 0.f;
      #pragma unroll
      for (int r=0;r<4;r++){
        float e = __expf(accT[jm][0][r] - m0);
        s0 += e;
        pv0 = fmaf(e, b2f(vgB[o*42 + quad*4 + r]), pv0);
      }
      #pragma unroll
      for (int r=0;r<4;r++){
        bool isp0 = (quad == 0), vld = (quad != 1);
        float mm = isp0 ? m0 : m1;
        float e  = vld ? __expf(accT[jm][1][r] - mm) : 0.f;
        int col  = isp0 ? (16 + r) : (vld ? (12 + quad*4 + r) : 0); // p1: 20+(quad*4+r-8)
        float vg = b2f(vgB[o*42 + col]);
        if (isp0){ s0 += e; pv0 = fmaf(e, vg, pv0); }
        else     { s1 += e; pv1 = fmaf(e, vg, pv1); }
      }
      #pragma unroll
      for (int r=0;r<4;r++){
        bool vld = (quad <= 2);
        float e = vld ? __expf(accT[jm][2][r] - m1) : 0.f;
        int col = vld ? (28 + quad*4 + r) : 0;
        s1 += e;
        pv1 = fmaf(e, b2f(vgB[o*42 + col]), pv1);
      }
      s0  += __shfl_xor(s0, 16);  s0  += __shfl_xor(s0, 32);
      s1  += __shfl_xor(s1, 16);  s1  += __shfl_xor(s1, 32);
      pv0 += __shfl_xor(pv0, 16); pv0 += __shfl_xor(pv0, 32);
      pv1 += __shfl_xor(pv1, 16); pv1 += __shfl_xor(pv1, 32);
      if (quad == 0){
        int rr = l15 & 3;
        *(short*)(unionB + UADDR(rr,     o*2)) = (short)f2b(__fdividef(pv0, s0));
        *(short*)(unionB + UADDR(4 + rr, o*2)) = (short)f2b(__fdividef(pv1, s1));
      }
    }
  }

  // ---- T14 prefetch for stage 5 — AFTER softmax (accT dead), before B7' ----
  float4 idv[4];
  if (l15 < 8){
    int p = l15 >> 2;
    #pragma unroll
    for (int jm=0;jm<4;jm++)
      idv[jm] = *reinterpret_cast<const float4*>(valueT + (bN + n0 + p)*Cq + (w*4+jm)*16 + quad*4);
  }
  short8 aweb[2][4];
  #pragma unroll
  for (int ks=0;ks<2;ks++)
    #pragma unroll
    for (int jm=0;jm<4;jm++)
      aweb[ks][jm] = *reinterpret_cast<const short8*>(web + (((w*4+jm)*2+ks)*64 + lane)*8);

  __syncthreads();                               // B7': aggB ready

  // ---- stage 5: conv_end (64->256) MFMA + bias + identity ----
  {
    f32x4 accE[4];
    #pragma unroll
    for (int jm=0;jm<4;jm++) accE[jm]=(f32x4)0.f;
    __builtin_amdgcn_s_setprio(1);
    #pragma unroll
    for (int ks=0;ks<2;ks++){
      const int kcolb = (ks*32 + quad*8)*2;
      short8 bb = *reinterpret_cast<const short8*>(unionB + UADDR(l15, kcolb));
      #pragma unroll
      for (int jm=0;jm<4;jm++){
        accE[jm] = __builtin_amdgcn_mfma_f32_16x16x32_bf16(aweb[ks][jm], bb, accE[jm], 0,0,0);
      }
    }
    __builtin_amdgcn_s_setprio(0);
    if (l15 < 8){
      int p = l15 >> 2, rr = l15 & 3;
      #pragma unroll
      for (int jm=0;jm<4;jm++){
        float4 b4 = *reinterpret_cast<const float4*>(be + (w*4+jm)*16 + quad*4);
        #pragma unroll
        for (int r=0;r<4;r++){
          int c = (w*4+jm)*16 + quad*4 + r;
          float y = accE[jm][r] + ((const float*)&b4)[r] + ((const float*)&idv[jm])[r];
          out[((size_t)(b*Cq+c))*((size_t)Nq*UPq) + (size_t)(n0+p)*UPq + rr] = y;
        }
      }
    }
  }
}

// ---------------------------------------------------------------------------
extern "C" void kernel_launch(void* const* d_in, const int* in_sizes, int n_in,
                              void* d_out, int out_size, void* d_ws, size_t ws_size,
                              hipStream_t stream)
{
  const float* pos  = (const float*)d_in[0];
  const float* key  = (const float*)d_in[1];
  const float* qry  = (const float*)d_in[2];
  const float* wv1  = (const float*)d_in[3];
  const float* bv1  = (const float*)d_in[4];
  const float* wv2  = (const float*)d_in[5];
  const float* bv2  = (const float*)d_in[6];
  const float* wvs  = (const float*)d_in[7];
  const float* bvs  = (const float*)d_in[8];
  const float* wk   = (const float*)d_in[9];
  const float* bk   = (const float*)d_in[10];
  const float* wq   = (const float*)d_in[11];
  const float* bq   = (const float*)d_in[12];
  const float* wval = (const float*)d_in[13];
  const float* bval = (const float*)d_in[14];
  const float* pw1  = (const float*)d_in[15];
  const float* pb1  = (const float*)d_in[16];
  const float* pg   = (const float*)d_in[17];
  const float* pbt  = (const float*)d_in[18];
  const float* prm  = (const float*)d_in[19];
  const float* prv  = (const float*)d_in[20];
  const float* pw2  = (const float*)d_in[21];
  const float* pb2  = (const float*)d_in[22];
  const float* aw1  = (const float*)d_in[23];
  const float* ab1  = (const float*)d_in[24];
  const float* ag   = (const float*)d_in[25];
  const float* abt  = (const float*)d_in[26];
  const float* arm  = (const float*)d_in[27];
  const float* arv  = (const float*)d_in[28];
  const float* ctw  = (const float*)d_in[29];
  const float* we   = (const float*)d_in[31];
  const float* be   = (const float*)d_in[32];

  char* ws = (char*)d_ws;
  float* valueT = (float*)(ws);                    // 8 MB fp32
  short* kfT    = (short*)(ws + 8388608);          // 1 MB bf16
  short* qfT    = (short*)(ws + 9437184);
  short* vfT    = (short*)(ws + 10485760);
  int*   idxT   = (int*)  (ws + 11534336);         // 640 KB
  short* aw1b   = (short*)(ws + 12189696);         // 32 KB
  short* ctwT   = (short*)(ws + 12222464);         // 128 KB
  short* wv1b   = (short*)(ws + 12353536);         // 256 KB
  short* wvsb   = (short*)(ws + 12615680);         // 256 KB
  short* wv2b   = (short*)(ws + 12877824);         // 128 KB
  short* wkb    = (short*)(ws + 13008896);         // 32 KB
  short* wqb    = (short*)(ws + 13041664);         // 32 KB
  short* wvalb  = (short*)(ws + 13074432);         // 32 KB
  short* pw2b   = (short*)(ws + 13107200);         // 8 KB
  short* web    = (short*)(ws + 13115392);         // 32 KB
  float* out    = (float*)d_out;

  k_prep<<<dim3(1872), dim3(256), 0, stream>>>(
      aw1, ctw, wv1, wvs, wv2, wk, wq, wval, pw2, we,
      aw1b, ctwT, wv1b, wvsb, wv2b, wkb, wqb, wvalb, pw2b, web,
      ag, arv);
  k_vk<<<dim3(2560), dim3(256), 0, stream>>>(
      key, qry, wv1b, wvsb, wv2b, wkb, wqb, wvalb,
      bv1, bv2, bvs, bk, bq, bval,
      valueT, kfT, qfT, vfT, pos, idxT);
  k_attn<<<dim3(Bq*Nq/2), dim3(256), 0, stream>>>(
      pos, valueT, kfT, qfT, vfT, idxT,
      pw1, pb1, pg, pbt, prm, prv, pw2b, pb2,
      aw1b, ab1, ag, abt, arm, arv, ctwT, web, be, out);
}

// Round 11
// 247.162 us; speedup vs baseline: 1.0526x; 1.0165x over previous
//
#include <hip/hip_runtime.h>
#include <hip/hip_bf16.h>

#define Bq 4
#define Nq 2048
#define Cq 256
#define Dq 64
#define UPq 4
#define KNNq 20
#define PHq 64
#define DMq 256   // D*MULT
#define PTS 16    // points per block in k_value

typedef __attribute__((ext_vector_type(8))) short short8;
typedef __attribute__((ext_vector_type(4))) short short4v;
typedef __attribute__((ext_vector_type(4))) float f32x4;
typedef __hip_bfloat16 bf16;

__device__ __forceinline__ unsigned short f2b(float x){
  bf16 h = __float2bfloat16(x);
  return *reinterpret_cast<unsigned short*>(&h);
}
__device__ __forceinline__ float b2f(short s){
  return __bfloat162float(*reinterpret_cast<bf16*>(&s));
}

// ---------------------------------------------------------------------------
// Kernel 0: weight prep — emit bf16 weights in MFMA A-fragment-swizzled order:
// dst[((mt*KS+ks)*64+lane)*8+j] = W[mt*16+(lane&15)][ks*32+(lane>>4)*8+j]
// aw1 additionally gets the attn-BN scale folded in (row scale ag*rsqrt(arv+eps)).
// ---------------------------------------------------------------------------
__device__ __forceinline__ void swz(const float* __restrict__ src,
                                    short* __restrict__ dst,
                                    int M, int K, int g, bool transp)
{
  int j = g & 7, lane = (g >> 3) & 63, rest = g >> 9;
  int KS = K >> 5;
  int ks = rest % KS, mt = rest / KS;
  int m = mt*16 + (lane & 15);
  int k = ks*32 + ((lane >> 4) << 3) + j;
  float v = transp ? src[k*M + m] : src[m*K + k];
  dst[g] = (short)f2b(v);
}

__device__ __forceinline__ void swz_s(const float* __restrict__ src,
                                      short* __restrict__ dst,
                                      int M, int K, int g,
                                      const float* __restrict__ gam,
                                      const float* __restrict__ var)
{
  int j = g & 7, lane = (g >> 3) & 63, rest = g >> 9;
  int KS = K >> 5;
  int ks = rest % KS, mt = rest / KS;
  int m = mt*16 + (lane & 15);
  int k = ks*32 + ((lane >> 4) << 3) + j;
  float sc = gam[m] * rsqrtf(var[m] + 1e-5f);
  dst[g] = (short)f2b(src[m*K + k] * sc);
}

__global__ __launch_bounds__(256) void k_prep(
    const float* __restrict__ aw1, const float* __restrict__ ctw,
    const float* __restrict__ wv1, const float* __restrict__ wvs,
    const float* __restrict__ wv2, const float* __restrict__ wk,
    const float* __restrict__ wq,  const float* __restrict__ wval,
    const float* __restrict__ pw2, const float* __restrict__ we,
    short* __restrict__ aw1b, short* __restrict__ ctwT,
    short* __restrict__ wv1b, short* __restrict__ wvsb,
    short* __restrict__ wv2b, short* __restrict__ wkb,
    short* __restrict__ wqb,  short* __restrict__ wvalb,
    short* __restrict__ pw2b, short* __restrict__ web,
    const float* __restrict__ ag, const float* __restrict__ arv)
{
  const int t = threadIdx.x, bidx = blockIdx.x;
  if (bidx < 512){
    swz(wv1, wv1b, 256, 512, bidx*256 + t, false);
  } else if (bidx < 1024){
    swz(wvs, wvsb, 256, 512, (bidx-512)*256 + t, false);
  } else if (bidx < 1280){
    swz(wv2, wv2b, 256, 256, (bidx-1024)*256 + t, false);
  } else if (bidx < 1344){
    swz(wk, wkb, 64, 256, (bidx-1280)*256 + t, false);
  } else if (bidx < 1408){
    swz(wq, wqb, 64, 256, (bidx-1344)*256 + t, false);
  } else if (bidx < 1472){
    swz(wval, wvalb, 64, 256, (bidx-1408)*256 + t, false);
  } else if (bidx < 1488){
    swz(pw2, pw2b, 64, 64, (bidx-1472)*256 + t, false);
  } else if (bidx < 1552){
    swz_s(aw1, aw1b, 256, 64, (bidx-1488)*256 + t, ag, arv);  // BN scale folded in
  } else if (bidx < 1616){
    swz(we, web, 256, 64, (bidx-1552)*256 + t, false);
  } else {
    swz(ctw, ctwT, 256, 256, (bidx-1616)*256 + t, true);  // W[m=t_out][k=c] = ctw[c][t_out]
  }
}

// ---------------------------------------------------------------------------
// Kernel 1: FUSED value-MLP + KNN ("k_vk").  (round-6 verified)
// ---------------------------------------------------------------------------
__global__ __launch_bounds__(256, 4) void k_vk(
    const float* __restrict__ key, const float* __restrict__ query,
    const short* __restrict__ wv1b, const short* __restrict__ wvsb,
    const short* __restrict__ wv2b, const short* __restrict__ wkb,
    const short* __restrict__ wqb,  const short* __restrict__ wvalb,
    const float* __restrict__ bv1, const float* __restrict__ bv2,
    const float* __restrict__ bvs, const float* __restrict__ bk,
    const float* __restrict__ bq,  const float* __restrict__ bval,
    float* __restrict__ valueT, short* __restrict__ kfT,
    short* __restrict__ qfT,    short* __restrict__ vfT,
    const float* __restrict__ pos, int* __restrict__ idxT)
{
  const int t = threadIdx.x;
  const int lane = t & 63, w = t >> 6;
  const int vb = blockIdx.x / 5, rem = blockIdx.x % 5;

  if (rem == 4){
    // ================= value path (block vb of 512) =================
    __shared__ __align__(16) short Xb[16*520];
    __shared__ __align__(16) short hidB[16*264];
    __shared__ __align__(16) short valB[16*264];
    const int b = vb >> 7;
    const int n0 = (vb & 127) * PTS;
    const int quad = lane >> 4, l15 = lane & 15;

    {
      const int c4 = t >> 2, pq = t & 3;
      #pragma unroll
      for (int pass=0; pass<4; pass++){
        int c = pass*64 + c4;
        float4 kv = *reinterpret_cast<const float4*>(key   + ((size_t)(b*Cq+c))*Nq + n0 + pq*4);
        float4 qv = *reinterpret_cast<const float4*>(query + ((size_t)(b*Cq+c))*Nq + n0 + pq*4);
        const float* kf_ = (const float*)&kv;
        const float* qf_ = (const float*)&qv;
        #pragma unroll
        for (int i=0;i<4;i++){
          Xb[(pq*4+i)*520 + c]       = (short)f2b(kf_[i]);
          Xb[(pq*4+i)*520 + 256 + c] = (short)f2b(qf_[i]);
        }
      }
    }
    __syncthreads();

    f32x4 acc1[4], accS[4];
    #pragma unroll
    for (int jm=0;jm<4;jm++){ acc1[jm]=(f32x4)0.f; accS[jm]=(f32x4)0.f; }

    #pragma unroll
    for (int ks=0;ks<16;ks++){
      const int kcol = ks*32 + quad*8;
      short8 xb = *reinterpret_cast<const short8*>(&Xb[l15*520 + kcol]);
      #pragma unroll
      for (int jm=0;jm<4;jm++){
        int mt = w*4 + jm;
        short8 a1 = *reinterpret_cast<const short8*>(wv1b + ((mt*16+ks)*64 + lane)*8);
        short8 as = *reinterpret_cast<const short8*>(wvsb + ((mt*16+ks)*64 + lane)*8);
        acc1[jm] = __builtin_amdgcn_mfma_f32_16x16x32_bf16(a1, xb, acc1[jm], 0,0,0);
        accS[jm] = __builtin_amdgcn_mfma_f32_16x16x32_bf16(as, xb, accS[jm], 0,0,0);
      }
    }
    #pragma unroll
    for (int jm=0;jm<4;jm++){
      #pragma unroll
      for (int r=0;r<4;r++){
        int h = (w*4+jm)*16 + quad*4 + r;
        hidB[l15*264 + h] = (short)f2b(fmaxf(acc1[jm][r] + bv1[h], 0.f));
      }
    }
    __syncthreads();

    #pragma unroll
    for (int ks=0;ks<8;ks++){
      const int kcol = ks*32 + quad*8;
      short8 hb = *reinterpret_cast<const short8*>(&hidB[l15*264 + kcol]);
      #pragma unroll
      for (int jm=0;jm<4;jm++){
        int mt = w*4 + jm;
        short8 a = *reinterpret_cast<const short8*>(wv2b + ((mt*8+ks)*64 + lane)*8);
        accS[jm] = __builtin_amdgcn_mfma_f32_16x16x32_bf16(a, hb, accS[jm], 0,0,0);
      }
    }
    #pragma unroll
    for (int jm=0;jm<4;jm++){
      const int cb = (w*4+jm)*16 + quad*4;
      float4 v4;
      #pragma unroll
      for (int r=0;r<4;r++){
        int c = cb + r;
        float v = accS[jm][r] + bv2[c] + bvs[c];
        ((float*)&v4)[r] = v;
        valB[l15*264 + c] = (short)f2b(v);
      }
      // direct fp32 write of value (identity path), 16B contiguous
      *reinterpret_cast<float4*>(valueT + ((size_t)(b*Nq + n0 + l15))*Cq + cb) = v4;
    }
    __syncthreads();

    {
      f32x4 pk4=(f32x4)0.f, pq4=(f32x4)0.f, pv4=(f32x4)0.f;
      #pragma unroll
      for (int ks=0;ks<8;ks++){
        const int kcol = ks*32 + quad*8;
        short8 xk = *reinterpret_cast<const short8*>(&Xb[l15*520 + kcol]);
        short8 xq = *reinterpret_cast<const short8*>(&Xb[l15*520 + 256 + kcol]);
        short8 xv = *reinterpret_cast<const short8*>(&valB[l15*264 + kcol]);
        short8 ak = *reinterpret_cast<const short8*>(wkb  + ((w*8+ks)*64 + lane)*8);
        short8 aq = *reinterpret_cast<const short8*>(wqb  + ((w*8+ks)*64 + lane)*8);
        short8 av = *reinterpret_cast<const short8*>(wvalb+ ((w*8+ks)*64 + lane)*8);
        pk4 = __builtin_amdgcn_mfma_f32_16x16x32_bf16(ak, xk, pk4, 0,0,0);
        pq4 = __builtin_amdgcn_mfma_f32_16x16x32_bf16(aq, xq, pq4, 0,0,0);
        pv4 = __builtin_amdgcn_mfma_f32_16x16x32_bf16(av, xv, pv4, 0,0,0);
      }
      short4v ok, oq, ov;
      #pragma unroll
      for (int r=0;r<4;r++){
        int o = w*16 + quad*4 + r;
        ok[r] = (short)f2b(pk4[r] + bk[o]);
        oq[r] = (short)f2b(pq4[r] + bq[o]);
        ov[r] = (short)f2b(pv4[r] + bval[o]);
      }
      int n = n0 + l15;
      size_t base = ((size_t)(b*Nq+n))*Dq + w*16 + quad*4;
      *reinterpret_cast<short4v*>(kfT + base) = ok;
      *reinterpret_cast<short4v*>(qfT + base) = oq;
      *reinterpret_cast<short4v*>(vfT + base) = ov;
    }
  } else {
    // ================= knn path (block kb of 2048) =================
    const int kb = vb*4 + rem;
    const int pid = kb*4 + w;
    const int b = pid >> 11;
    const int n = pid & (Nq-1);
    const float* px = pos + (size_t)(b*3+0)*Nq;
    const float* py = pos + (size_t)(b*3+1)*Nq;
    const float* pz = pos + (size_t)(b*3+2)*Nq;
    const float xn=px[n], yn=py[n], zn=pz[n];
    const float sqn = __fadd_rn(__fadd_rn(__fmul_rn(xn,xn),__fmul_rn(yn,yn)),__fmul_rn(zn,zn));

    double kd[32];
    #pragma unroll
    for (int i=0;i<32;i++){
      int j = i*64 + lane;
      float x=px[j], y=py[j], z=pz[j];
      float sqj = __fadd_rn(__fadd_rn(__fmul_rn(x,x),__fmul_rn(y,y)),__fmul_rn(z,z));
      float dot = __fadd_rn(__fadd_rn(__fmul_rn(xn,x),__fmul_rn(yn,y)),__fmul_rn(zn,z));
      float d   = __fsub_rn(__fadd_rn(sqn,sqj), __fmul_rn(2.0f,dot));
      unsigned u = __float_as_uint(d);
      u ^= ((unsigned)((int)u >> 31)) | 0x80000000u;
      kd[i] = (double)u * 2048.0 + (double)j;
    }

    const double BIG = 9.0e15;
    // ---- build per-lane sorted top-4 buffer (b0<=b1<=b2<=b3) ----
    double b0=BIG, b1=BIG, b2=BIG, b3=BIG;
    #pragma unroll
    for (int i=0;i<32;i++){
      double x = kd[i];
      double M0 = fmax(b0, x);  b0 = fmin(b0, x);
      double M1 = fmax(b1, M0); b1 = fmin(b1, M0);
      double M2 = fmax(b2, M1); b2 = fmin(b2, M1);
      b3 = fmin(b3, M2);
    }

    double lane_last = -1.0;
    int cnt = 0;
    for (int s=0;s<KNNq;s++){
      // global min of buffer heads
      double m = b0;
      #pragma unroll
      for (int off=1; off<64; off<<=1)
        m = fmin(m, __shfl_xor(m, off));
      if (lane == 0){
        unsigned long long kk = (unsigned long long)m;
        idxT[(size_t)pid*KNNq + s] = (int)(kk & 2047ull);
      }
      // owner pops (keys unique -> exactly one lane)
      if (b0 == m){
        lane_last = b0;
        b0 = b1; b1 = b2; b2 = b3; b3 = BIG;
        cnt++;
      }
      // rare refill: lane exhausted its 4-buffer
      if (__any(cnt >= 4)){
        if (cnt >= 4){
          b0 = BIG; b1 = BIG; b2 = BIG; b3 = BIG;
          #pragma unroll
          for (int i=0;i<32;i++){
            double x = (kd[i] > lane_last) ? kd[i] : BIG;
            double M0 = fmax(b0, x);  b0 = fmin(b0, x);
            double M1 = fmax(b1, M0); b1 = fmin(b1, M0);
            double M2 = fmax(b2, M1); b2 = fmin(b2, M1);
            b3 = fmin(b3, M2);
          }
          cnt = 0;
        }
      }
    }
  }
}

// ---------------------------------------------------------------------------
// Kernel 3: fused attn, P=2 points per block (round-8 verified BEST config).
// Session ledger (rounds 7-10): occupancy is register-capped at 4 waves/SIMD
// (5 waves -> accumulator spill, r7); extending accT's live range through an
// in-register softmax also spills (r9/r10: +18-40 MB scratch traffic/dispatch)
// -> the ctS LDS round-trip (accT dies immediately after stage 4) is the
// register-feasible optimum of this decomposition.
//   - vgB stride 42 shorts (odd dword stride: conflict-free softmax reads)
//   - T14 prefetch: ctwT ksl=0 frags before pre-stage-4 barrier; web before B9
//   - T5 setprio(1) around stage-3/4/5 MFMA clusters
// LDS 40,448 B -> 4 blocks/CU, VGPR 64, no spill (FETCH 18.5 / WRITE 41 MB).
// ---------------------------------------------------------------------------
#define UADDR(row, colb) ((((row)*128 + (colb)) ^ (((row)&7)<<4)))
#define SADDR(row, colb) ((((row)*256 + (colb)) ^ (((row)&7)<<4)))

__global__ __launch_bounds__(256, 4) void k_attn(
  const float* __restrict__ pos,
  const float* __restrict__ valueT, const short* __restrict__ kfT,
  const short* __restrict__ qfT,    const short* __restrict__ vfT,
  const int* __restrict__ idxT,
  const float* __restrict__ pw1, const float* __restrict__ pb1,
  const float* __restrict__ pg,  const float* __restrict__ pbt,
  const float* __restrict__ prm, const float* __restrict__ prv,
  const short* __restrict__ pw2b, const float* __restrict__ pb2,
  const short* __restrict__ aw1b, const float* __restrict__ ab1,
  const float* __restrict__ ag,  const float* __restrict__ abt,
  const float* __restrict__ arm, const float* __restrict__ arv,
  const short* __restrict__ ctwT,
  const short* __restrict__ web,  const float* __restrict__ be,
  float* __restrict__ out)
{
  // unionA: [0,12288) sT(48x128 swz) | [12288,13312) sh2S ; later all ctS(256x44)
  __shared__ __align__(16) char unionA[22528];
  // unionB: hB(48x64 swz) -> aggB(rows 0..7 valid, 64 swz)
  __shared__ __align__(16) char unionB[6144];
  // unionC: init: prl(3x48 f32)+nb(48 int) ; stage2+: uT(48x64 swz)
  __shared__ __align__(16) char unionC[6144];
  __shared__ __align__(16) short vgB[64*42];   // [o][p*20+k], stride 42 (odd dwords)

  float* sh2S = (float*)(unionA + 12288);
  float* prl  = (float*)unionC;
  int*   nb   = (int*)(unionC + 576);

  const int t = threadIdx.x;
  const int b  = blockIdx.x >> 10;
  const int n0 = (blockIdx.x & 1023) * 2;
  const int lane = t & 63, quad = lane >> 4, l15 = lane & 15, w = t >> 6;
  const size_t bN = (size_t)b * Nq;
  const int obase = w*16 + quad*4;

  if (t < 48){
    int p = (t >= 24);
    int k = t - p*24;
    int nn = n0 + p;
    int j = (k < KNNq) ? idxT[(bN + nn)*KNNq + k] : nn;
    nb[t] = j;
    #pragma unroll
    for (int d=0; d<3; d++){
      prl[d*48+t] = pos[((size_t)(b*3+d))*Nq + nn] - pos[((size_t)(b*3+d))*Nq + j];
    }
  }
  {
    float sc = ag[t] * rsqrtf(arv[t] + 1e-5f);
    sh2S[t]  = ab1[t]*sc + (abt[t] - arm[t]*sc);
  }
  __syncthreads();                               // B1

  // ---- prefetch q/k/v fragments (consumed in stage-2 epilogue) ----
  short4v pq4[3], pk4[3], pv4[3];
  #pragma unroll
  for (int nt=0; nt<3; nt++){
    int pk = nt*16 + l15;
    int p  = (pk >= 24);
    int j  = nb[pk];
    pq4[nt] = *reinterpret_cast<const short4v*>(qfT + (bN + n0 + p)*Dq + obase);
    pk4[nt] = *reinterpret_cast<const short4v*>(kfT + (bN + j)*Dq + obase);
    pv4[nt] = *reinterpret_cast<const short4v*>(vfT + (bN + j)*Dq + obase);
  }

  // ---- stage 1: pos_mlp hidden -> hB (BN folded into weights here) ----
  {
    const int ph = t & 63;
    float sc = pg[ph] * rsqrtf(prv[ph] + 1e-5f);
    float w0 = pw1[ph*3+0]*sc, w1 = pw1[ph*3+1]*sc, w2 = pw1[ph*3+2]*sc;
    float bb = pb1[ph]*sc + (pbt[ph] - prm[ph]*sc);
    #pragma unroll
    for (int m=0;m<12;m++){
      int pk = w + m*4;
      float h = fmaf(w0, prl[pk], fmaf(w1, prl[48+pk], fmaf(w2, prl[96+pk], bb)));
      *(short*)(unionB + UADDR(pk, ph*2)) = (short)f2b(fmaxf(h, 0.f));
    }
  }
  __syncthreads();                               // B2

  // ---- stage 2: pos_emb via MFMA; epilogue builds uT, vgB ----
  {
    f32x4 accP[3];
    #pragma unroll
    for (int nt=0;nt<3;nt++) accP[nt]=(f32x4)0.f;
    #pragma unroll
    for (int ks=0;ks<2;ks++){
      const int kcolb = (ks*32 + quad*8)*2;
      short8 a = *reinterpret_cast<const short8*>(pw2b + ((w*2+ks)*64 + lane)*8);
      #pragma unroll
      for (int nt=0;nt<3;nt++){
        short8 bb = *reinterpret_cast<const short8*>(unionB + UADDR(nt*16+l15, kcolb));
        accP[nt] = __builtin_amdgcn_mfma_f32_16x16x32_bf16(a, bb, accP[nt], 0,0,0);
      }
    }
    #pragma unroll
    for (int nt=0;nt<3;nt++){
      int pk = nt*16 + l15;
      bool vld = (pk < 20) || (pk >= 24 && pk < 44);
      int col  = pk - (pk >= 24 ? 4 : 0);
      short4v ut4;
      #pragma unroll
      for (int r=0;r<4;r++){
        int o = obase + r;
        float pe = accP[nt][r] + pb2[o];
        ut4[r] = (short)f2b((b2f(pq4[nt][r]) - b2f(pk4[nt][r])) + pe);
        if (vld) vgB[o*42 + col] = (short)f2b(b2f(pv4[nt][r]) + pe);
      }
      *(short4v*)(unionC + UADDR(pk, obase*2)) = ut4;
    }
  }
  __syncthreads();                               // B3 (hB dead, prl/nb dead)

  // ---- stages 3+4 chunked over hidden cols (2 x 128); accT spans chunks ----
  f32x4 accT[4][3];
  #pragma unroll
  for (int jm=0;jm<4;jm++)
    #pragma unroll
    for (int nt=0;nt<3;nt++) accT[jm][nt]=(f32x4)0.f;

  #pragma unroll
  for (int ch=0; ch<2; ch++){
    // stage 3 partial: hidden cols [ch*128, ch*128+128)
    f32x4 accC[2][3];
    #pragma unroll
    for (int jm=0;jm<2;jm++)
      #pragma unroll
      for (int nt=0;nt<3;nt++) accC[jm][nt]=(f32x4)0.f;
    __builtin_amdgcn_s_setprio(1);
    #pragma unroll
    for (int ks=0;ks<2;ks++){
      const int kcolb = (ks*32 + quad*8)*2;
      short8 bb[3];
      #pragma unroll
      for (int nt=0;nt<3;nt++)
        bb[nt] = *reinterpret_cast<const short8*>(unionC + UADDR(nt*16+l15, kcolb));
      #pragma unroll
      for (int jm=0;jm<2;jm++){
        int mt = ch*8 + w*2 + jm;
        short8 a = *reinterpret_cast<const short8*>(aw1b + ((mt*2+ks)*64 + lane)*8);
        #pragma unroll
        for (int nt=0;nt<3;nt++)
          accC[jm][nt] = __builtin_amdgcn_mfma_f32_16x16x32_bf16(a, bb[nt], accC[jm][nt], 0,0,0);
      }
    }
    __builtin_amdgcn_s_setprio(0);

    // T14: prefetch stage-4 ksl=0 A-frags (static L2 addrs) before the barrier
    short8 actw0[4];
    #pragma unroll
    for (int jm=0;jm<4;jm++)
      actw0[jm] = *reinterpret_cast<const short8*>(ctwT + (((w*4+jm)*8 + ch*4)*64 + lane)*8);

    if (ch == 1) __syncthreads();                // B5: stage4-c0 done reading sT
    #pragma unroll
    for (int jm=0;jm<2;jm++){
      const int colb = ((w*2+jm)*16 + quad*4)*2;
      #pragma unroll
      for (int nt=0;nt<3;nt++){
        int pk = nt*16 + l15;
        short4v pkv;
        #pragma unroll
        for (int r=0;r<4;r++){
          int c = ch*128 + (w*2+jm)*16 + quad*4 + r;
          pkv[r] = (short)f2b(fmaxf(accC[jm][nt][r] + sh2S[c], 0.f));
        }
        *(short4v*)(unionA + SADDR(pk, colb)) = pkv;
      }
    }
    __syncthreads();                             // B4 / B6: sT chunk visible
    __builtin_amdgcn_s_setprio(1);
    #pragma unroll
    for (int ksl=0; ksl<4; ksl++){
      const int kcolb = (ksl*32 + quad*8)*2;
      short8 bb[3];
      #pragma unroll
      for (int nt=0;nt<3;nt++)
        bb[nt] = *reinterpret_cast<const short8*>(unionA + SADDR(nt*16+l15, kcolb));
      #pragma unroll
      for (int jm=0;jm<4;jm++){
        int mt = w*4 + jm;
        short8 a = (ksl == 0) ? actw0[jm]
                 : *reinterpret_cast<const short8*>(ctwT + ((mt*8 + ch*4 + ksl)*64 + lane)*8);
        #pragma unroll
        for (int nt=0;nt<3;nt++)
          accT[jm][nt] = __builtin_amdgcn_mfma_f32_16x16x32_bf16(a, bb[nt], accT[jm][nt], 0,0,0);
      }
    }
    __builtin_amdgcn_s_setprio(0);
  }
  __syncthreads();                               // B7: sT/sh2S dead -> ctS free

  // ---- ct -> ctS (compact: only valid k; stride 44 shorts) ----
  #pragma unroll
  for (int nt=0;nt<3;nt++){
    int pk = nt*16 + l15;
    bool vld = (pk < 20) || (pk >= 24 && pk < 44);
    int col  = pk - (pk >= 24 ? 4 : 0);
    if (vld){
      #pragma unroll
      for (int jm=0;jm<4;jm++){
        #pragma unroll
        for (int r=0;r<4;r++){
          int row = (w*4+jm)*16 + quad*4 + r;
          *(short*)(unionA + row*88 + col*2) = (short)f2b(accT[jm][nt][r]);
        }
      }
    }
  }
  __syncthreads();                               // B8

  // ---- softmax + aggregate; prefetch identity + web frags for stage 5 ----
  float4 idv[4];
  if (l15 < 8){
    int p = l15 >> 2;
    #pragma unroll
    for (int jm=0;jm<4;jm++)
      idv[jm] = *reinterpret_cast<const float4*>(valueT + (bN + n0 + p)*Cq + (w*4+jm)*16 + quad*4);
  }
  // T14: prefetch stage-5 A-frags (static L2 addrs) before B9
  short8 aweb[2][4];
  #pragma unroll
  for (int ks=0;ks<2;ks++)
    #pragma unroll
    for (int jm=0;jm<4;jm++)
      aweb[ks][jm] = *reinterpret_cast<const short8*>(web + (((w*4+jm)*2+ks)*64 + lane)*8);
  {
    const int o = t >> 2, rr = t & 3;
    #pragma unroll
    for (int p=0;p<2;p++){
      float ct[20];
      #pragma unroll
      for (int q=0;q<5;q++){
        short4v cv = *reinterpret_cast<const short4v*>(unionA + t*88 + p*40 + q*8);
        #pragma unroll
        for (int i=0;i<4;i++) ct[q*4+i] = b2f(cv[i]);
      }
      float m = ct[0];
      #pragma unroll
      for (int k=1;k<20;k++) m = fmaxf(m, ct[k]);
      float s = 0.f, a = 0.f;
      #pragma unroll
      for (int q=0;q<5;q++){
        short4v vv = *reinterpret_cast<const short4v*>((const char*)vgB + o*84 + p*40 + q*8);
        #pragma unroll
        for (int i=0;i<4;i++){
          float e = __expf(ct[q*4+i] - m);
          s += e;
          a = fmaf(e, b2f(vv[i]), a);
        }
      }
      *(short*)(unionB + UADDR(p*4+rr, o*2)) = (short)f2b(__fdividef(a, s));
    }
  }
  __syncthreads();                               // B9

  // ---- stage 5: conv_end (64->256) MFMA + bias + identity ----
  {
    f32x4 accE[4];
    #pragma unroll
    for (int jm=0;jm<4;jm++) accE[jm]=(f32x4)0.f;
    __builtin_amdgcn_s_setprio(1);
    #pragma unroll
    for (int ks=0;ks<2;ks++){
      const int kcolb = (ks*32 + quad*8)*2;
      short8 bb = *reinterpret_cast<const short8*>(unionB + UADDR(l15, kcolb));
      #pragma unroll
      for (int jm=0;jm<4;jm++){
        accE[jm] = __builtin_amdgcn_mfma_f32_16x16x32_bf16(aweb[ks][jm], bb, accE[jm], 0,0,0);
      }
    }
    __builtin_amdgcn_s_setprio(0);
    if (l15 < 8){
      int p = l15 >> 2, rr = l15 & 3;
      #pragma unroll
      for (int jm=0;jm<4;jm++){
        float4 b4 = *reinterpret_cast<const float4*>(be + (w*4+jm)*16 + quad*4);
        #pragma unroll
        for (int r=0;r<4;r++){
          int c = (w*4+jm)*16 + quad*4 + r;
          float y = accE[jm][r] + ((const float*)&b4)[r] + ((const float*)&idv[jm])[r];
          out[((size_t)(b*Cq+c))*((size_t)Nq*UPq) + (size_t)(n0+p)*UPq + rr] = y;
        }
      }
    }
  }
}

// ---------------------------------------------------------------------------
extern "C" void kernel_launch(void* const* d_in, const int* in_sizes, int n_in,
                              void* d_out, int out_size, void* d_ws, size_t ws_size,
                              hipStream_t stream)
{
  const float* pos  = (const float*)d_in[0];
  const float* key  = (const float*)d_in[1];
  const float* qry  = (const float*)d_in[2];
  const float* wv1  = (const float*)d_in[3];
  const float* bv1  = (const float*)d_in[4];
  const float* wv2  = (const float*)d_in[5];
  const float* bv2  = (const float*)d_in[6];
  const float* wvs  = (const float*)d_in[7];
  const float* bvs  = (const float*)d_in[8];
  const float* wk   = (const float*)d_in[9];
  const float* bk   = (const float*)d_in[10];
  const float* wq   = (const float*)d_in[11];
  const float* bq   = (const float*)d_in[12];
  const float* wval = (const float*)d_in[13];
  const float* bval = (const float*)d_in[14];
  const float* pw1  = (const float*)d_in[15];
  const float* pb1  = (const float*)d_in[16];
  const float* pg   = (const float*)d_in[17];
  const float* pbt  = (const float*)d_in[18];
  const float* prm  = (const float*)d_in[19];
  const float* prv  = (const float*)d_in[20];
  const float* pw2  = (const float*)d_in[21];
  const float* pb2  = (const float*)d_in[22];
  const float* aw1  = (const float*)d_in[23];
  const float* ab1  = (const float*)d_in[24];
  const float* ag   = (const float*)d_in[25];
  const float* abt  = (const float*)d_in[26];
  const float* arm  = (const float*)d_in[27];
  const float* arv  = (const float*)d_in[28];
  const float* ctw  = (const float*)d_in[29];
  const float* we   = (const float*)d_in[31];
  const float* be   = (const float*)d_in[32];

  char* ws = (char*)d_ws;
  float* valueT = (float*)(ws);                    // 8 MB fp32
  short* kfT    = (short*)(ws + 8388608);          // 1 MB bf16
  short* qfT    = (short*)(ws + 9437184);
  short* vfT    = (short*)(ws + 10485760);
  int*   idxT   = (int*)  (ws + 11534336);         // 640 KB
  short* aw1b   = (short*)(ws + 12189696);         // 32 KB
  short* ctwT   = (short*)(ws + 12222464);         // 128 KB
  short* wv1b   = (short*)(ws + 12353536);         // 256 KB
  short* wvsb   = (short*)(ws + 12615680);         // 256 KB
  short* wv2b   = (short*)(ws + 12877824);         // 128 KB
  short* wkb    = (short*)(ws + 13008896);         // 32 KB
  short* wqb    = (short*)(ws + 13041664);         // 32 KB
  short* wvalb  = (short*)(ws + 13074432);         // 32 KB
  short* pw2b   = (short*)(ws + 13107200);         // 8 KB
  short* web    = (short*)(ws + 13115392);         // 32 KB
  float* out    = (float*)d_out;

  k_prep<<<dim3(1872), dim3(256), 0, stream>>>(
      aw1, ctw, wv1, wvs, wv2, wk, wq, wval, pw2, we,
      aw1b, ctwT, wv1b, wvsb, wv2b, wkb, wqb, wvalb, pw2b, web,
      ag, arv);
  k_vk<<<dim3(2560), dim3(256), 0, stream>>>(
      key, qry, wv1b, wvsb, wv2b, wkb, wqb, wvalb,
      bv1, bv2, bvs, bk, bq, bval,
      valueT, kfT, qfT, vfT, pos, idxT);
  k_attn<<<dim3(Bq*Nq/2), dim3(256), 0, stream>>>(
      pos, valueT, kfT, qfT, vfT, idxT,
      pw1, pb1, pg, pbt, prm, prv, pw2b, pb2,
      aw1b, ab1, ag, abt, arm, arv, ctwT, web, be, out);
}

// Round 12
// 243.072 us; speedup vs baseline: 1.0703x; 1.0168x over previous
//
#include <hip/hip_runtime.h>
#include <hip/hip_bf16.h>

#define Bq 4
#define Nq 2048
#define Cq 256
#define Dq 64
#define UPq 4
#define KNNq 20
#define PHq 64
#define DMq 256   // D*MULT
#define PTS 16    // points per block in k_value

typedef __attribute__((ext_vector_type(8))) short short8;
typedef __attribute__((ext_vector_type(4))) short short4v;
typedef __attribute__((ext_vector_type(4))) float f32x4;
typedef __hip_bfloat16 bf16;

__device__ __forceinline__ unsigned short f2b(float x){
  bf16 h = __float2bfloat16(x);
  return *reinterpret_cast<unsigned short*>(&h);
}
__device__ __forceinline__ float b2f(short s){
  return __bfloat162float(*reinterpret_cast<bf16*>(&s));
}

// ---------------------------------------------------------------------------
// Kernel 0: weight prep — emit bf16 weights in MFMA A-fragment-swizzled order:
// dst[((mt*KS+ks)*64+lane)*8+j] = W[mt*16+(lane&15)][ks*32+(lane>>4)*8+j]
// aw1 additionally gets the attn-BN scale folded in (row scale ag*rsqrt(arv+eps)).
// ---------------------------------------------------------------------------
__device__ __forceinline__ void swz(const float* __restrict__ src,
                                    short* __restrict__ dst,
                                    int M, int K, int g, bool transp)
{
  int j = g & 7, lane = (g >> 3) & 63, rest = g >> 9;
  int KS = K >> 5;
  int ks = rest % KS, mt = rest / KS;
  int m = mt*16 + (lane & 15);
  int k = ks*32 + ((lane >> 4) << 3) + j;
  float v = transp ? src[k*M + m] : src[m*K + k];
  dst[g] = (short)f2b(v);
}

__device__ __forceinline__ void swz_s(const float* __restrict__ src,
                                      short* __restrict__ dst,
                                      int M, int K, int g,
                                      const float* __restrict__ gam,
                                      const float* __restrict__ var)
{
  int j = g & 7, lane = (g >> 3) & 63, rest = g >> 9;
  int KS = K >> 5;
  int ks = rest % KS, mt = rest / KS;
  int m = mt*16 + (lane & 15);
  int k = ks*32 + ((lane >> 4) << 3) + j;
  float sc = gam[m] * rsqrtf(var[m] + 1e-5f);
  dst[g] = (short)f2b(src[m*K + k] * sc);
}

__global__ __launch_bounds__(256) void k_prep(
    const float* __restrict__ aw1, const float* __restrict__ ctw,
    const float* __restrict__ wv1, const float* __restrict__ wvs,
    const float* __restrict__ wv2, const float* __restrict__ wk,
    const float* __restrict__ wq,  const float* __restrict__ wval,
    const float* __restrict__ pw2, const float* __restrict__ we,
    short* __restrict__ aw1b, short* __restrict__ ctwT,
    short* __restrict__ wv1b, short* __restrict__ wvsb,
    short* __restrict__ wv2b, short* __restrict__ wkb,
    short* __restrict__ wqb,  short* __restrict__ wvalb,
    short* __restrict__ pw2b, short* __restrict__ web,
    const float* __restrict__ ag, const float* __restrict__ arv)
{
  const int t = threadIdx.x, bidx = blockIdx.x;
  if (bidx < 512){
    swz(wv1, wv1b, 256, 512, bidx*256 + t, false);
  } else if (bidx < 1024){
    swz(wvs, wvsb, 256, 512, (bidx-512)*256 + t, false);
  } else if (bidx < 1280){
    swz(wv2, wv2b, 256, 256, (bidx-1024)*256 + t, false);
  } else if (bidx < 1344){
    swz(wk, wkb, 64, 256, (bidx-1280)*256 + t, false);
  } else if (bidx < 1408){
    swz(wq, wqb, 64, 256, (bidx-1344)*256 + t, false);
  } else if (bidx < 1472){
    swz(wval, wvalb, 64, 256, (bidx-1408)*256 + t, false);
  } else if (bidx < 1488){
    swz(pw2, pw2b, 64, 64, (bidx-1472)*256 + t, false);
  } else if (bidx < 1552){
    swz_s(aw1, aw1b, 256, 64, (bidx-1488)*256 + t, ag, arv);  // BN scale folded in
  } else if (bidx < 1616){
    swz(we, web, 256, 64, (bidx-1552)*256 + t, false);
  } else {
    swz(ctw, ctwT, 256, 256, (bidx-1616)*256 + t, true);  // W[m=t_out][k=c] = ctw[c][t_out]
  }
}

// ---------------------------------------------------------------------------
// Kernel 1: FUSED value-MLP + KNN ("k_vk").
// Round-12: KNN pop loop extracts TWO neighbors per butterfly via pair-merge
// reduction over each lane's sorted head pair (b0,b1): rounds 20 -> 10,
// halving the dependent cross-lane shfl chain (the knn path's dominant
// latency). Merge op = "two smallest of union" (associative/commutative/
// idempotent -> valid XOR-butterfly all-reduce). Global 1st+2nd smallest
// remaining always live in some lane's (b0,b1). Pops ascending (m1<m2) ->
// idxT order identical; refill at cnt>=3 (need 2 valid heads), same filter
// -> bit-identical indices.
// ---------------------------------------------------------------------------
__global__ __launch_bounds__(256, 4) void k_vk(
    const float* __restrict__ key, const float* __restrict__ query,
    const short* __restrict__ wv1b, const short* __restrict__ wvsb,
    const short* __restrict__ wv2b, const short* __restrict__ wkb,
    const short* __restrict__ wqb,  const short* __restrict__ wvalb,
    const float* __restrict__ bv1, const float* __restrict__ bv2,
    const float* __restrict__ bvs, const float* __restrict__ bk,
    const float* __restrict__ bq,  const float* __restrict__ bval,
    float* __restrict__ valueT, short* __restrict__ kfT,
    short* __restrict__ qfT,    short* __restrict__ vfT,
    const float* __restrict__ pos, int* __restrict__ idxT)
{
  const int t = threadIdx.x;
  const int lane = t & 63, w = t >> 6;
  const int vb = blockIdx.x / 5, rem = blockIdx.x % 5;

  if (rem == 4){
    // ================= value path (block vb of 512) =================
    __shared__ __align__(16) short Xb[16*520];
    __shared__ __align__(16) short hidB[16*264];
    __shared__ __align__(16) short valB[16*264];
    const int b = vb >> 7;
    const int n0 = (vb & 127) * PTS;
    const int quad = lane >> 4, l15 = lane & 15;

    {
      const int c4 = t >> 2, pq = t & 3;
      #pragma unroll
      for (int pass=0; pass<4; pass++){
        int c = pass*64 + c4;
        float4 kv = *reinterpret_cast<const float4*>(key   + ((size_t)(b*Cq+c))*Nq + n0 + pq*4);
        float4 qv = *reinterpret_cast<const float4*>(query + ((size_t)(b*Cq+c))*Nq + n0 + pq*4);
        const float* kf_ = (const float*)&kv;
        const float* qf_ = (const float*)&qv;
        #pragma unroll
        for (int i=0;i<4;i++){
          Xb[(pq*4+i)*520 + c]       = (short)f2b(kf_[i]);
          Xb[(pq*4+i)*520 + 256 + c] = (short)f2b(qf_[i]);
        }
      }
    }
    __syncthreads();

    f32x4 acc1[4], accS[4];
    #pragma unroll
    for (int jm=0;jm<4;jm++){ acc1[jm]=(f32x4)0.f; accS[jm]=(f32x4)0.f; }

    #pragma unroll
    for (int ks=0;ks<16;ks++){
      const int kcol = ks*32 + quad*8;
      short8 xb = *reinterpret_cast<const short8*>(&Xb[l15*520 + kcol]);
      #pragma unroll
      for (int jm=0;jm<4;jm++){
        int mt = w*4 + jm;
        short8 a1 = *reinterpret_cast<const short8*>(wv1b + ((mt*16+ks)*64 + lane)*8);
        short8 as = *reinterpret_cast<const short8*>(wvsb + ((mt*16+ks)*64 + lane)*8);
        acc1[jm] = __builtin_amdgcn_mfma_f32_16x16x32_bf16(a1, xb, acc1[jm], 0,0,0);
        accS[jm] = __builtin_amdgcn_mfma_f32_16x16x32_bf16(as, xb, accS[jm], 0,0,0);
      }
    }
    #pragma unroll
    for (int jm=0;jm<4;jm++){
      #pragma unroll
      for (int r=0;r<4;r++){
        int h = (w*4+jm)*16 + quad*4 + r;
        hidB[l15*264 + h] = (short)f2b(fmaxf(acc1[jm][r] + bv1[h], 0.f));
      }
    }
    __syncthreads();

    #pragma unroll
    for (int ks=0;ks<8;ks++){
      const int kcol = ks*32 + quad*8;
      short8 hb = *reinterpret_cast<const short8*>(&hidB[l15*264 + kcol]);
      #pragma unroll
      for (int jm=0;jm<4;jm++){
        int mt = w*4 + jm;
        short8 a = *reinterpret_cast<const short8*>(wv2b + ((mt*8+ks)*64 + lane)*8);
        accS[jm] = __builtin_amdgcn_mfma_f32_16x16x32_bf16(a, hb, accS[jm], 0,0,0);
      }
    }
    #pragma unroll
    for (int jm=0;jm<4;jm++){
      const int cb = (w*4+jm)*16 + quad*4;
      float4 v4;
      #pragma unroll
      for (int r=0;r<4;r++){
        int c = cb + r;
        float v = accS[jm][r] + bv2[c] + bvs[c];
        ((float*)&v4)[r] = v;
        valB[l15*264 + c] = (short)f2b(v);
      }
      // direct fp32 write of value (identity path), 16B contiguous
      *reinterpret_cast<float4*>(valueT + ((size_t)(b*Nq + n0 + l15))*Cq + cb) = v4;
    }
    __syncthreads();

    {
      f32x4 pk4=(f32x4)0.f, pq4=(f32x4)0.f, pv4=(f32x4)0.f;
      #pragma unroll
      for (int ks=0;ks<8;ks++){
        const int kcol = ks*32 + quad*8;
        short8 xk = *reinterpret_cast<const short8*>(&Xb[l15*520 + kcol]);
        short8 xq = *reinterpret_cast<const short8*>(&Xb[l15*520 + 256 + kcol]);
        short8 xv = *reinterpret_cast<const short8*>(&valB[l15*264 + kcol]);
        short8 ak = *reinterpret_cast<const short8*>(wkb  + ((w*8+ks)*64 + lane)*8);
        short8 aq = *reinterpret_cast<const short8*>(wqb  + ((w*8+ks)*64 + lane)*8);
        short8 av = *reinterpret_cast<const short8*>(wvalb+ ((w*8+ks)*64 + lane)*8);
        pk4 = __builtin_amdgcn_mfma_f32_16x16x32_bf16(ak, xk, pk4, 0,0,0);
        pq4 = __builtin_amdgcn_mfma_f32_16x16x32_bf16(aq, xq, pq4, 0,0,0);
        pv4 = __builtin_amdgcn_mfma_f32_16x16x32_bf16(av, xv, pv4, 0,0,0);
      }
      short4v ok, oq, ov;
      #pragma unroll
      for (int r=0;r<4;r++){
        int o = w*16 + quad*4 + r;
        ok[r] = (short)f2b(pk4[r] + bk[o]);
        oq[r] = (short)f2b(pq4[r] + bq[o]);
        ov[r] = (short)f2b(pv4[r] + bval[o]);
      }
      int n = n0 + l15;
      size_t base = ((size_t)(b*Nq+n))*Dq + w*16 + quad*4;
      *reinterpret_cast<short4v*>(kfT + base) = ok;
      *reinterpret_cast<short4v*>(qfT + base) = oq;
      *reinterpret_cast<short4v*>(vfT + base) = ov;
    }
  } else {
    // ================= knn path (block kb of 2048) =================
    const int kb = vb*4 + rem;
    const int pid = kb*4 + w;
    const int b = pid >> 11;
    const int n = pid & (Nq-1);
    const float* px = pos + (size_t)(b*3+0)*Nq;
    const float* py = pos + (size_t)(b*3+1)*Nq;
    const float* pz = pos + (size_t)(b*3+2)*Nq;
    const float xn=px[n], yn=py[n], zn=pz[n];
    const float sqn = __fadd_rn(__fadd_rn(__fmul_rn(xn,xn),__fmul_rn(yn,yn)),__fmul_rn(zn,zn));

    double kd[32];
    #pragma unroll
    for (int i=0;i<32;i++){
      int j = i*64 + lane;
      float x=px[j], y=py[j], z=pz[j];
      float sqj = __fadd_rn(__fadd_rn(__fmul_rn(x,x),__fmul_rn(y,y)),__fmul_rn(z,z));
      float dot = __fadd_rn(__fadd_rn(__fmul_rn(xn,x),__fmul_rn(yn,y)),__fmul_rn(zn,z));
      float d   = __fsub_rn(__fadd_rn(sqn,sqj), __fmul_rn(2.0f,dot));
      unsigned u = __float_as_uint(d);
      u ^= ((unsigned)((int)u >> 31)) | 0x80000000u;
      kd[i] = (double)u * 2048.0 + (double)j;
    }

    const double BIG = 9.0e15;
    // ---- build per-lane sorted top-4 buffer (b0<=b1<=b2<=b3) ----
    double b0=BIG, b1=BIG, b2=BIG, b3=BIG;
    #pragma unroll
    for (int i=0;i<32;i++){
      double x = kd[i];
      double M0 = fmax(b0, x);  b0 = fmin(b0, x);
      double M1 = fmax(b1, M0); b1 = fmin(b1, M0);
      double M2 = fmax(b2, M1); b2 = fmin(b2, M1);
      b3 = fmin(b3, M2);
    }

    double lane_last = -1.0;
    int cnt = 0;
    for (int s=0;s<KNNq;s+=2){
      // global (1st,2nd)-smallest over all lanes' sorted head pairs (b0,b1)
      double m1 = b0, m2 = b1;
      #pragma unroll
      for (int off=1; off<64; off<<=1){
        double o1 = __shfl_xor(m1, off);
        double o2 = __shfl_xor(m2, off);
        double lo = fmin(m1, o1);
        double hi = fmax(m1, o1);
        m2 = fmin(hi, fmin(m2, o2));
        m1 = lo;
      }
      if (lane == 0){
        unsigned long long k1 = (unsigned long long)m1;
        unsigned long long k2 = (unsigned long long)m2;
        idxT[(size_t)pid*KNNq + s]     = (int)(k1 & 2047ull);
        idxT[(size_t)pid*KNNq + s + 1] = (int)(k2 & 2047ull);
      }
      // pops (keys unique -> owners well-defined; one lane may own both)
      if (b0 == m1){
        if (b1 == m2){
          lane_last = b1;
          b0 = b2; b1 = b3; b2 = BIG; b3 = BIG;
          cnt += 2;
        } else {
          lane_last = b0;
          b0 = b1; b1 = b2; b2 = b3; b3 = BIG;
          cnt++;
        }
      } else if (b0 == m2){
        lane_last = b0;
        b0 = b1; b1 = b2; b2 = b3; b3 = BIG;
        cnt++;
      }
      // refill when fewer than 2 valid heads could remain (cnt>=3)
      if (__any(cnt >= 3)){
        if (cnt >= 3){
          b0 = BIG; b1 = BIG; b2 = BIG; b3 = BIG;
          #pragma unroll
          for (int i=0;i<32;i++){
            double x = (kd[i] > lane_last) ? kd[i] : BIG;
            double M0 = fmax(b0, x);  b0 = fmin(b0, x);
            double M1 = fmax(b1, M0); b1 = fmin(b1, M0);
            double M2 = fmax(b2, M1); b2 = fmin(b2, M1);
            b3 = fmin(b3, M2);
          }
          cnt = 0;
        }
      }
    }
  }
}

// ---------------------------------------------------------------------------
// Kernel 3: fused attn, P=2 points per block (round-8 verified BEST config).
// Session ledger (rounds 7-10): occupancy is register-capped at 4 waves/SIMD
// (5 waves -> accumulator spill, r7); extending accT's live range through an
// in-register softmax also spills (r9/r10: +18-40 MB scratch traffic/dispatch)
// -> the ctS LDS round-trip (accT dies immediately after stage 4) is the
// register-feasible optimum of this decomposition.
//   - vgB stride 42 shorts (odd dword stride: conflict-free softmax reads)
//   - T14 prefetch: ctwT ksl=0 frags before pre-stage-4 barrier; web before B9
//   - T5 setprio(1) around stage-3/4/5 MFMA clusters
// LDS 40,448 B -> 4 blocks/CU, VGPR 64, no spill (FETCH 18.5 / WRITE 41 MB).
// ---------------------------------------------------------------------------
#define UADDR(row, colb) ((((row)*128 + (colb)) ^ (((row)&7)<<4)))
#define SADDR(row, colb) ((((row)*256 + (colb)) ^ (((row)&7)<<4)))

__global__ __launch_bounds__(256, 4) void k_attn(
  const float* __restrict__ pos,
  const float* __restrict__ valueT, const short* __restrict__ kfT,
  const short* __restrict__ qfT,    const short* __restrict__ vfT,
  const int* __restrict__ idxT,
  const float* __restrict__ pw1, const float* __restrict__ pb1,
  const float* __restrict__ pg,  const float* __restrict__ pbt,
  const float* __restrict__ prm, const float* __restrict__ prv,
  const short* __restrict__ pw2b, const float* __restrict__ pb2,
  const short* __restrict__ aw1b, const float* __restrict__ ab1,
  const float* __restrict__ ag,  const float* __restrict__ abt,
  const float* __restrict__ arm, const float* __restrict__ arv,
  const short* __restrict__ ctwT,
  const short* __restrict__ web,  const float* __restrict__ be,
  float* __restrict__ out)
{
  // unionA: [0,12288) sT(48x128 swz) | [12288,13312) sh2S ; later all ctS(256x44)
  __shared__ __align__(16) char unionA[22528];
  // unionB: hB(48x64 swz) -> aggB(rows 0..7 valid, 64 swz)
  __shared__ __align__(16) char unionB[6144];
  // unionC: init: prl(3x48 f32)+nb(48 int) ; stage2+: uT(48x64 swz)
  __shared__ __align__(16) char unionC[6144];
  __shared__ __align__(16) short vgB[64*42];   // [o][p*20+k], stride 42 (odd dwords)

  float* sh2S = (float*)(unionA + 12288);
  float* prl  = (float*)unionC;
  int*   nb   = (int*)(unionC + 576);

  const int t = threadIdx.x;
  const int b  = blockIdx.x >> 10;
  const int n0 = (blockIdx.x & 1023) * 2;
  const int lane = t & 63, quad = lane >> 4, l15 = lane & 15, w = t >> 6;
  const size_t bN = (size_t)b * Nq;
  const int obase = w*16 + quad*4;

  if (t < 48){
    int p = (t >= 24);
    int k = t - p*24;
    int nn = n0 + p;
    int j = (k < KNNq) ? idxT[(bN + nn)*KNNq + k] : nn;
    nb[t] = j;
    #pragma unroll
    for (int d=0; d<3; d++){
      prl[d*48+t] = pos[((size_t)(b*3+d))*Nq + nn] - pos[((size_t)(b*3+d))*Nq + j];
    }
  }
  {
    float sc = ag[t] * rsqrtf(arv[t] + 1e-5f);
    sh2S[t]  = ab1[t]*sc + (abt[t] - arm[t]*sc);
  }
  __syncthreads();                               // B1

  // ---- prefetch q/k/v fragments (consumed in stage-2 epilogue) ----
  short4v pq4[3], pk4[3], pv4[3];
  #pragma unroll
  for (int nt=0; nt<3; nt++){
    int pk = nt*16 + l15;
    int p  = (pk >= 24);
    int j  = nb[pk];
    pq4[nt] = *reinterpret_cast<const short4v*>(qfT + (bN + n0 + p)*Dq + obase);
    pk4[nt] = *reinterpret_cast<const short4v*>(kfT + (bN + j)*Dq + obase);
    pv4[nt] = *reinterpret_cast<const short4v*>(vfT + (bN + j)*Dq + obase);
  }

  // ---- stage 1: pos_mlp hidden -> hB (BN folded into weights here) ----
  {
    const int ph = t & 63;
    float sc = pg[ph] * rsqrtf(prv[ph] + 1e-5f);
    float w0 = pw1[ph*3+0]*sc, w1 = pw1[ph*3+1]*sc, w2 = pw1[ph*3+2]*sc;
    float bb = pb1[ph]*sc + (pbt[ph] - prm[ph]*sc);
    #pragma unroll
    for (int m=0;m<12;m++){
      int pk = w + m*4;
      float h = fmaf(w0, prl[pk], fmaf(w1, prl[48+pk], fmaf(w2, prl[96+pk], bb)));
      *(short*)(unionB + UADDR(pk, ph*2)) = (short)f2b(fmaxf(h, 0.f));
    }
  }
  __syncthreads();                               // B2

  // ---- stage 2: pos_emb via MFMA; epilogue builds uT, vgB ----
  {
    f32x4 accP[3];
    #pragma unroll
    for (int nt=0;nt<3;nt++) accP[nt]=(f32x4)0.f;
    #pragma unroll
    for (int ks=0;ks<2;ks++){
      const int kcolb = (ks*32 + quad*8)*2;
      short8 a = *reinterpret_cast<const short8*>(pw2b + ((w*2+ks)*64 + lane)*8);
      #pragma unroll
      for (int nt=0;nt<3;nt++){
        short8 bb = *reinterpret_cast<const short8*>(unionB + UADDR(nt*16+l15, kcolb));
        accP[nt] = __builtin_amdgcn_mfma_f32_16x16x32_bf16(a, bb, accP[nt], 0,0,0);
      }
    }
    #pragma unroll
    for (int nt=0;nt<3;nt++){
      int pk = nt*16 + l15;
      bool vld = (pk < 20) || (pk >= 24 && pk < 44);
      int col  = pk - (pk >= 24 ? 4 : 0);
      short4v ut4;
      #pragma unroll
      for (int r=0;r<4;r++){
        int o = obase + r;
        float pe = accP[nt][r] + pb2[o];
        ut4[r] = (short)f2b((b2f(pq4[nt][r]) - b2f(pk4[nt][r])) + pe);
        if (vld) vgB[o*42 + col] = (short)f2b(b2f(pv4[nt][r]) + pe);
      }
      *(short4v*)(unionC + UADDR(pk, obase*2)) = ut4;
    }
  }
  __syncthreads();                               // B3 (hB dead, prl/nb dead)

  // ---- stages 3+4 chunked over hidden cols (2 x 128); accT spans chunks ----
  f32x4 accT[4][3];
  #pragma unroll
  for (int jm=0;jm<4;jm++)
    #pragma unroll
    for (int nt=0;nt<3;nt++) accT[jm][nt]=(f32x4)0.f;

  #pragma unroll
  for (int ch=0; ch<2; ch++){
    // stage 3 partial: hidden cols [ch*128, ch*128+128)
    f32x4 accC[2][3];
    #pragma unroll
    for (int jm=0;jm<2;jm++)
      #pragma unroll
      for (int nt=0;nt<3;nt++) accC[jm][nt]=(f32x4)0.f;
    __builtin_amdgcn_s_setprio(1);
    #pragma unroll
    for (int ks=0;ks<2;ks++){
      const int kcolb = (ks*32 + quad*8)*2;
      short8 bb[3];
      #pragma unroll
      for (int nt=0;nt<3;nt++)
        bb[nt] = *reinterpret_cast<const short8*>(unionC + UADDR(nt*16+l15, kcolb));
      #pragma unroll
      for (int jm=0;jm<2;jm++){
        int mt = ch*8 + w*2 + jm;
        short8 a = *reinterpret_cast<const short8*>(aw1b + ((mt*2+ks)*64 + lane)*8);
        #pragma unroll
        for (int nt=0;nt<3;nt++)
          accC[jm][nt] = __builtin_amdgcn_mfma_f32_16x16x32_bf16(a, bb[nt], accC[jm][nt], 0,0,0);
      }
    }
    __builtin_amdgcn_s_setprio(0);

    // T14: prefetch stage-4 ksl=0 A-frags (static L2 addrs) before the barrier
    short8 actw0[4];
    #pragma unroll
    for (int jm=0;jm<4;jm++)
      actw0[jm] = *reinterpret_cast<const short8*>(ctwT + (((w*4+jm)*8 + ch*4)*64 + lane)*8);

    if (ch == 1) __syncthreads();                // B5: stage4-c0 done reading sT
    #pragma unroll
    for (int jm=0;jm<2;jm++){
      const int colb = ((w*2+jm)*16 + quad*4)*2;
      #pragma unroll
      for (int nt=0;nt<3;nt++){
        int pk = nt*16 + l15;
        short4v pkv;
        #pragma unroll
        for (int r=0;r<4;r++){
          int c = ch*128 + (w*2+jm)*16 + quad*4 + r;
          pkv[r] = (short)f2b(fmaxf(accC[jm][nt][r] + sh2S[c], 0.f));
        }
        *(short4v*)(unionA + SADDR(pk, colb)) = pkv;
      }
    }
    __syncthreads();                             // B4 / B6: sT chunk visible
    __builtin_amdgcn_s_setprio(1);
    #pragma unroll
    for (int ksl=0; ksl<4; ksl++){
      const int kcolb = (ksl*32 + quad*8)*2;
      short8 bb[3];
      #pragma unroll
      for (int nt=0;nt<3;nt++)
        bb[nt] = *reinterpret_cast<const short8*>(unionA + SADDR(nt*16+l15, kcolb));
      #pragma unroll
      for (int jm=0;jm<4;jm++){
        int mt = w*4 + jm;
        short8 a = (ksl == 0) ? actw0[jm]
                 : *reinterpret_cast<const short8*>(ctwT + ((mt*8 + ch*4 + ksl)*64 + lane)*8);
        #pragma unroll
        for (int nt=0;nt<3;nt++)
          accT[jm][nt] = __builtin_amdgcn_mfma_f32_16x16x32_bf16(a, bb[nt], accT[jm][nt], 0,0,0);
      }
    }
    __builtin_amdgcn_s_setprio(0);
  }
  __syncthreads();                               // B7: sT/sh2S dead -> ctS free

  // ---- ct -> ctS (compact: only valid k; stride 44 shorts) ----
  #pragma unroll
  for (int nt=0;nt<3;nt++){
    int pk = nt*16 + l15;
    bool vld = (pk < 20) || (pk >= 24 && pk < 44);
    int col  = pk - (pk >= 24 ? 4 : 0);
    if (vld){
      #pragma unroll
      for (int jm=0;jm<4;jm++){
        #pragma unroll
        for (int r=0;r<4;r++){
          int row = (w*4+jm)*16 + quad*4 + r;
          *(short*)(unionA + row*88 + col*2) = (short)f2b(accT[jm][nt][r]);
        }
      }
    }
  }
  __syncthreads();                               // B8

  // ---- softmax + aggregate; prefetch identity + web frags for stage 5 ----
  float4 idv[4];
  if (l15 < 8){
    int p = l15 >> 2;
    #pragma unroll
    for (int jm=0;jm<4;jm++)
      idv[jm] = *reinterpret_cast<const float4*>(valueT + (bN + n0 + p)*Cq + (w*4+jm)*16 + quad*4);
  }
  // T14: prefetch stage-5 A-frags (static L2 addrs) before B9
  short8 aweb[2][4];
  #pragma unroll
  for (int ks=0;ks<2;ks++)
    #pragma unroll
    for (int jm=0;jm<4;jm++)
      aweb[ks][jm] = *reinterpret_cast<const short8*>(web + (((w*4+jm)*2+ks)*64 + lane)*8);
  {
    const int o = t >> 2, rr = t & 3;
    #pragma unroll
    for (int p=0;p<2;p++){
      float ct[20];
      #pragma unroll
      for (int q=0;q<5;q++){
        short4v cv = *reinterpret_cast<const short4v*>(unionA + t*88 + p*40 + q*8);
        #pragma unroll
        for (int i=0;i<4;i++) ct[q*4+i] = b2f(cv[i]);
      }
      float m = ct[0];
      #pragma unroll
      for (int k=1;k<20;k++) m = fmaxf(m, ct[k]);
      float s = 0.f, a = 0.f;
      #pragma unroll
      for (int q=0;q<5;q++){
        short4v vv = *reinterpret_cast<const short4v*>((const char*)vgB + o*84 + p*40 + q*8);
        #pragma unroll
        for (int i=0;i<4;i++){
          float e = __expf(ct[q*4+i] - m);
          s += e;
          a = fmaf(e, b2f(vv[i]), a);
        }
      }
      *(short*)(unionB + UADDR(p*4+rr, o*2)) = (short)f2b(__fdividef(a, s));
    }
  }
  __syncthreads();                               // B9

  // ---- stage 5: conv_end (64->256) MFMA + bias + identity ----
  {
    f32x4 accE[4];
    #pragma unroll
    for (int jm=0;jm<4;jm++) accE[jm]=(f32x4)0.f;
    __builtin_amdgcn_s_setprio(1);
    #pragma unroll
    for (int ks=0;ks<2;ks++){
      const int kcolb = (ks*32 + quad*8)*2;
      short8 bb = *reinterpret_cast<const short8*>(unionB + UADDR(l15, kcolb));
      #pragma unroll
      for (int jm=0;jm<4;jm++){
        accE[jm] = __builtin_amdgcn_mfma_f32_16x16x32_bf16(aweb[ks][jm], bb, accE[jm], 0,0,0);
      }
    }
    __builtin_amdgcn_s_setprio(0);
    if (l15 < 8){
      int p = l15 >> 2, rr = l15 & 3;
      #pragma unroll
      for (int jm=0;jm<4;jm++){
        float4 b4 = *reinterpret_cast<const float4*>(be + (w*4+jm)*16 + quad*4);
        #pragma unroll
        for (int r=0;r<4;r++){
          int c = (w*4+jm)*16 + quad*4 + r;
          float y = accE[jm][r] + ((const float*)&b4)[r] + ((const float*)&idv[jm])[r];
          out[((size_t)(b*Cq+c))*((size_t)Nq*UPq) + (size_t)(n0+p)*UPq + rr] = y;
        }
      }
    }
  }
}

// ---------------------------------------------------------------------------
extern "C" void kernel_launch(void* const* d_in, const int* in_sizes, int n_in,
                              void* d_out, int out_size, void* d_ws, size_t ws_size,
                              hipStream_t stream)
{
  const float* pos  = (const float*)d_in[0];
  const float* key  = (const float*)d_in[1];
  const float* qry  = (const float*)d_in[2];
  const float* wv1  = (const float*)d_in[3];
  const float* bv1  = (const float*)d_in[4];
  const float* wv2  = (const float*)d_in[5];
  const float* bv2  = (const float*)d_in[6];
  const float* wvs  = (const float*)d_in[7];
  const float* bvs  = (const float*)d_in[8];
  const float* wk   = (const float*)d_in[9];
  const float* bk   = (const float*)d_in[10];
  const float* wq   = (const float*)d_in[11];
  const float* bq   = (const float*)d_in[12];
  const float* wval = (const float*)d_in[13];
  const float* bval = (const float*)d_in[14];
  const float* pw1  = (const float*)d_in[15];
  const float* pb1  = (const float*)d_in[16];
  const float* pg   = (const float*)d_in[17];
  const float* pbt  = (const float*)d_in[18];
  const float* prm  = (const float*)d_in[19];
  const float* prv  = (const float*)d_in[20];
  const float* pw2  = (const float*)d_in[21];
  const float* pb2  = (const float*)d_in[22];
  const float* aw1  = (const float*)d_in[23];
  const float* ab1  = (const float*)d_in[24];
  const float* ag   = (const float*)d_in[25];
  const float* abt  = (const float*)d_in[26];
  const float* arm  = (const float*)d_in[27];
  const float* arv  = (const float*)d_in[28];
  const float* ctw  = (const float*)d_in[29];
  const float* we   = (const float*)d_in[31];
  const float* be   = (const float*)d_in[32];

  char* ws = (char*)d_ws;
  float* valueT = (float*)(ws);                    // 8 MB fp32
  short* kfT    = (short*)(ws + 8388608);          // 1 MB bf16
  short* qfT    = (short*)(ws + 9437184);
  short* vfT    = (short*)(ws + 10485760);
  int*   idxT   = (int*)  (ws + 11534336);         // 640 KB
  short* aw1b   = (short*)(ws + 12189696);         // 32 KB
  short* ctwT   = (short*)(ws + 12222464);         // 128 KB
  short* wv1b   = (short*)(ws + 12353536);         // 256 KB
  short* wvsb   = (short*)(ws + 12615680);         // 256 KB
  short* wv2b   = (short*)(ws + 12877824);         // 128 KB
  short* wkb    = (short*)(ws + 13008896);         // 32 KB
  short* wqb    = (short*)(ws + 13041664);         // 32 KB
  short* wvalb  = (short*)(ws + 13074432);         // 32 KB
  short* pw2b   = (short*)(ws + 13107200);         // 8 KB
  short* web    = (short*)(ws + 13115392);         // 32 KB
  float* out    = (float*)d_out;

  k_prep<<<dim3(1872), dim3(256), 0, stream>>>(
      aw1, ctw, wv1, wvs, wv2, wk, wq, wval, pw2, we,
      aw1b, ctwT, wv1b, wvsb, wv2b, wkb, wqb, wvalb, pw2b, web,
      ag, arv);
  k_vk<<<dim3(2560), dim3(256), 0, stream>>>(
      key, qry, wv1b, wvsb, wv2b, wkb, wqb, wvalb,
      bv1, bv2, bvs, bk, bq, bval,
      valueT, kfT, qfT, vfT, pos, idxT);
  k_attn<<<dim3(Bq*Nq/2), dim3(256), 0, stream>>>(
      pos, valueT, kfT, qfT, vfT, idxT,
      pw1, pb1, pg, pbt, prm, prv, pw2b, pb2,
      aw1b, ab1, ag, abt, arm, arv, ctwT, web, be, out);
}